// Round 18
// baseline (337.584 us; speedup 1.0000x reference)
//
#include <hip/hip_runtime.h>
#include <cstddef>
#include <cstdint>

#define BB 8
#define MD 256
#define NP 4096
#define HH 8
#define FF 16
#define SS 32
#define S3 32768
#define CC 152      // H*(F+3)
#define KC 24       // H*3
#define PTS (BB*HH*NP)   // 262144
#define BPT (HH*NP)      // points per batch = 32768
#define BN_CNT (BB*NP)   // 32768
#define EPSV 1e-5f
#define ZSTRH (HH*S3*FF)     // per-batch lattice ushorts (bf16) = 4,194,304 (8 MB)

typedef __attribute__((ext_vector_type(8))) short short8v;
typedef __attribute__((ext_vector_type(4))) float f32x4;

__device__ __forceinline__ unsigned int f2bf(float f) {
    unsigned int u = __float_as_uint(f);
    unsigned int r = u + 0x7FFFu + ((u >> 16) & 1u);   // round-to-nearest-even
    return r >> 16;
}

// ---- pack W_kv into MFMA A-frag lane order, SPLIT bf16 (hi + lo) ----------
__global__ __launch_bounds__(256) void k_wgpack(const float* __restrict__ W,
                                                unsigned short* __restrict__ wg) {
    int gid = blockIdx.x * 256 + threadIdx.x;     // 10*8*64 = 5120
    if (gid >= 5120) return;
    int lane = gid & 63;
    int mc   = (gid >> 6) & 7;
    int oct  = gid >> 9;
    int oc = oct * 16 + (lane & 15);
    int m0 = mc * 32 + (lane >> 4) * 8;
    unsigned short oh[8], ol[8];
#pragma unroll
    for (int j = 0; j < 8; ++j) {
        float wv = (oc < CC) ? W[(size_t)oc * MD + m0 + j] : 0.f;
        unsigned int hi = f2bf(wv);
        float r = wv - __uint_as_float(hi << 16);
        oh[j] = (unsigned short)hi;
        ol[j] = (unsigned short)f2bf(r);
    }
    ushort4* dh = (ushort4*)(wg + (size_t)gid * 8);
    dh[0] = make_ushort4(oh[0], oh[1], oh[2], oh[3]);
    dh[1] = make_ushort4(oh[4], oh[5], oh[6], oh[7]);
    ushort4* dl = (ushort4*)(wg + (size_t)(5120 + gid) * 8);
    dl[0] = make_ushort4(ol[0], ol[1], ol[2], ol[3]);
    dl[1] = make_ushort4(ol[4], ol[5], ol[6], ol[7]);
}

// ------ GEMM via split-bf16 MFMA: kv = W x, near-fp32 accurate -------------
__global__ __launch_bounds__(256) void k_gemm(const float* __restrict__ x,
                                              const unsigned short* __restrict__ wg,
                                              float* __restrict__ kv) {
    __shared__ __align__(16) unsigned char xh[32768];    // [64 n][256 m] bf16 swz
    __shared__ __align__(16) unsigned char xlo[32768];
    int nt = blockIdx.x;          // 0..63
    int b  = blockIdx.y;
    int tid = threadIdx.x;
    int n_l = tid & 63, w = tid >> 6;
    int n0 = nt * 64;

    const float* xb = x + (size_t)b * MD * NP + n0;
#pragma unroll 4
    for (int k = 0; k < 32; ++k) {
        int m = k * 8 + w * 2;
        float v0 = xb[(size_t)m * NP + n_l];
        float v1 = xb[(size_t)(m + 1) * NP + n_l];
        unsigned int h0 = f2bf(v0), h1 = f2bf(v1);
        float r0 = v0 - __uint_as_float(h0 << 16);
        float r1 = v1 - __uint_as_float(h1 << 16);
        unsigned int byte = (unsigned)(n_l * 512 + m * 2) ^ (unsigned)((n_l & 7) << 4);
        *(unsigned int*)(xh + byte)  = h0 | (h1 << 16);
        *(unsigned int*)(xlo + byte) = f2bf(r0) | (f2bf(r1) << 16);
    }
    __syncthreads();

    int lane = tid & 63;
    int nn = w * 16 + (lane & 15);
    int kg = lane >> 4;
    short8v xfh[8], xfl[8];
#pragma unroll
    for (int mc = 0; mc < 8; ++mc) {
        unsigned int byte = (unsigned)(nn * 512 + (mc * 32 + kg * 8) * 2)
                          ^ (unsigned)((nn & 7) << 4);
        xfh[mc] = *(const short8v*)(xh + byte);
        xfl[mc] = *(const short8v*)(xlo + byte);
    }

    f32x4 acc[10];
#pragma unroll
    for (int t = 0; t < 10; ++t) acc[t] = (f32x4){0.f, 0.f, 0.f, 0.f};

    const short8v* wfh = (const short8v*)wg;
    const short8v* wfl = wfh + 5120;
#pragma unroll
    for (int oct = 0; oct < 10; ++oct) {
#pragma unroll
        for (int mc = 0; mc < 8; ++mc) {
            short8v wh = wfh[(oct * 8 + mc) * 64 + lane];
            short8v wl = wfl[(oct * 8 + mc) * 64 + lane];
            acc[oct] = __builtin_amdgcn_mfma_f32_16x16x32_bf16(wh, xfh[mc], acc[oct], 0, 0, 0);
            acc[oct] = __builtin_amdgcn_mfma_f32_16x16x32_bf16(wh, xfl[mc], acc[oct], 0, 0, 0);
            acc[oct] = __builtin_amdgcn_mfma_f32_16x16x32_bf16(wl, xfh[mc], acc[oct], 0, 0, 0);
        }
    }

    int n = n0 + nn;
#pragma unroll
    for (int oct = 0; oct < 10; ++oct) {
#pragma unroll
        for (int r = 0; r < 4; ++r) {
            int oc = oct * 16 + kg * 4 + r;
            if (oc < CC)
                kv[((size_t)b * CC + oc) * NP + n] = acc[oct][r];
        }
    }
}

// ------------- BN stats over (B,N) for all 152 kv channels -----------------
__global__ __launch_bounds__(256) void k_stats_kv(const float* __restrict__ kv,
                                                  const float* __restrict__ kg,
                                                  const float* __restrict__ kb,
                                                  const float* __restrict__ vg,
                                                  const float* __restrict__ vb,
                                                  float* __restrict__ A,
                                                  float* __restrict__ Bv) {
    int o = blockIdx.x, tid = threadIdx.x;
    float s = 0.f, ss = 0.f;
    for (int b = 0; b < BB; ++b) {
        const float* p = kv + ((size_t)b * CC + o) * NP;
        for (int n = tid; n < NP; n += 256) { float v = p[n]; s += v; ss = fmaf(v, v, ss); }
    }
#pragma unroll
    for (int off = 32; off > 0; off >>= 1) { s += __shfl_down(s, off); ss += __shfl_down(ss, off); }
    __shared__ float sh[8];
    int lane = tid & 63, w = tid >> 6;
    if (lane == 0) { sh[w] = s; sh[4 + w] = ss; }
    __syncthreads();
    if (tid == 0) {
        float S_ = sh[0] + sh[1] + sh[2] + sh[3];
        float SSv = sh[4] + sh[5] + sh[6] + sh[7];
        float mean = S_ * (1.f / BN_CNT);
        float var  = SSv * (1.f / BN_CNT) - mean * mean;
        float rstd = rsqrtf(var + EPSV);
        float g  = (o < KC) ? kg[o] : vg[o - KC];
        float be = (o < KC) ? kb[o] : vb[o - KC];
        A[o]  = rstd * g;
        Bv[o] = be - mean * rstd * g;
    }
}

// --- per-point: BN keys -> affine -> tanh -> idx/frac; also emit vals[.,16] -
__global__ __launch_bounds__(256) void k_prep(const float* __restrict__ kv,
                                              const float* __restrict__ pcd,
                                              const float* __restrict__ A,
                                              const float* __restrict__ Bv,
                                              const float* __restrict__ R,
                                              const float* __restrict__ t,
                                              int* __restrict__ base,
                                              float* __restrict__ frac,
                                              float* __restrict__ vals) {
    int gid = blockIdx.x * 256 + threadIdx.x;
    int b = gid >> 15, h = (gid >> 12) & 7, n = gid & 4095;

    float p[3];
#pragma unroll
    for (int i = 0; i < 3; ++i) {
        int c = h * 3 + i;
        float v = kv[((size_t)b * CC + c) * NP + n];
        p[i] = pcd[((size_t)b * 3 + i) * NP + n] + fmaf(A[c], v, Bv[c]);
    }
    int fl[3]; float fr[3];
#pragma unroll
    for (int i = 0; i < 3; ++i) {
        float key = R[h * 9 + i * 3 + 0] * p[0] + R[h * 9 + i * 3 + 1] * p[1] +
                    R[h * 9 + i * 3 + 2] * p[2] + t[h * 3 + i];
        float lat = tanhf(key);
        float pos = (lat + 1.f) * 0.5f * (SS - 1);
        float flf = fminf(fmaxf(floorf(pos), 0.f), (float)(SS - 2));
        fr[i] = pos - flf;
        fl[i] = (int)flf;
    }
    base[gid] = (fl[0] * SS + fl[1]) * SS + fl[2];
    frac[gid]           = fr[0];
    frac[PTS + gid]     = fr[1];
    frac[2 * PTS + gid] = fr[2];

    float4* vo = (float4*)(vals + (size_t)gid * 16);
#pragma unroll
    for (int q = 0; q < 4; ++q) {
        float4 v;
        float* vv = (float*)&v;
#pragma unroll
        for (int j = 0; j < 4; ++j) {
            int c = KC + h * FF + q * 4 + j;
            vv[j] = fmaf(A[c], kv[((size_t)b * CC + c) * NP + n], Bv[c]);
        }
        vo[q] = v;
    }
}

// ---- counting sort per (b,h): 1024 (slab,y) bins -> sorted records --------
__global__ __launch_bounds__(256) void k_bin(const int* __restrict__ base,
                                             const float* __restrict__ frac,
                                             int4* __restrict__ sorted,
                                             int* __restrict__ bin_start) {
    __shared__ int hist[1024];
    __shared__ int curs[1024];
    int bh = blockIdx.x;           // b*8+h  (gid = bh*NP + n)
    int tid = threadIdx.x;
    for (int k = tid; k < 1024; k += 256) hist[k] = 0;
    __syncthreads();
    int gb = bh * NP;
    for (int p = tid; p < NP; p += 256)
        atomicAdd(&hist[base[gb + p] >> 5], 1);
    __syncthreads();
    if (tid == 0) {
        int run = 0;
        for (int k = 0; k < 1024; ++k) { int c = hist[k]; hist[k] = run; run += c; }
    }
    __syncthreads();
    for (int k = tid; k < 1024; k += 256) {
        bin_start[bh * 1024 + k] = hist[k];
        curs[k] = hist[k];
    }
    __syncthreads();
    for (int p = tid; p < NP; p += 256) {
        int bs = base[gb + p];
        int slot = atomicAdd(&curs[bs >> 5], 1);
        sorted[(size_t)bh * NP + slot] =
            make_int4(p | (bs << 12),
                      __float_as_int(frac[gb + p]),
                      __float_as_int(frac[PTS + gb + p]),
                      __float_as_int(frac[2 * PTS + gb + p]));
    }
}

// ---- permute vals into sorted-bin order: vals_s[j] = vals[sorted[j].p] ----
__global__ __launch_bounds__(256) void k_vperm(const int4* __restrict__ sorted,
                                               const float* __restrict__ vals,
                                               float* __restrict__ vals_s) {
    int gid = blockIdx.x * 256 + threadIdx.x;    // over PTS*4 quads
    int j = gid >> 2, q = gid & 3;
    int bh = j >> 12;
    int p = sorted[j].x & 4095;
    float4 v = ((const float4*)(vals + ((size_t)bh * NP + p) * 16))[q];
    ((float4*)(vals_s + (size_t)j * 16))[q] = v;
}

// ---- pack conv weights into MFMA A-fragment lane order (bf16) -------------
__global__ __launch_bounds__(256) void k_wpack(const float* __restrict__ cw,
                                               unsigned short* __restrict__ wApack) {
    int gid = blockIdx.x * 256 + threadIdx.x;     // (h*14 + m)*64 + lane
    if (gid >= 8 * 14 * 64) return;
    int lane = gid & 63;
    int m = (gid >> 6) % 14;
    int h = gid / (14 * 64);
    int fo = lane & 15, g = lane >> 4;
    int tap = 2 * m + (g >> 1);
    int ci0 = (g & 1) * 8;
    unsigned short o[8];
#pragma unroll
    for (int j = 0; j < 8; ++j) {
        float w = (tap <= 26) ? cw[((size_t)(h * 16 + fo) * 16 + ci0 + j) * 27 + tap] : 0.f;
        o[j] = (unsigned short)f2bf(w);
    }
    ushort4* dst = (ushort4*)(wApack + (size_t)gid * 8);
    dst[0] = make_ushort4(o[0], o[1], o[2], o[3]);
    dst[1] = make_ushort4(o[4], o[5], o[6], o[7]);
}

// --- splat: half-plane blocks, 16-record deep batched loads ----------------
// 4 waves/block, wave w owns global rows [yh*16 + 4w, +4); no LDS atomics;
// (slab,y)-sorted bins give each wave a contiguous y-window scan.
__global__ __launch_bounds__(256) void k_splat(const int4* __restrict__ sorted,
                                               const int* __restrict__ bin_start,
                                               const float* __restrict__ vsrc,
                                               unsigned short* __restrict__ zout,
                                               int b0, int sortedVals) {
    __shared__ float zl[16][32][16];         // 32 KB fp32 accumulate
    int x  = blockIdx.x;          // 0..31 output plane
    int yh = blockIdx.y;          // 0..1  y half
    int hq = blockIdx.z;          // h + 8*bq
    int h = hq & 7, bq = hq >> 3;
    int bh = (b0 + bq) * 8 + h;
    int tid = threadIdx.x;
    int wid = tid >> 6, lane = tid & 63;
    int ch = lane & 15, cor = lane >> 4;
    int dyb = cor >> 1, dzb = cor & 1;
    int row0 = yh * 16;
    int row_lo = row0 + wid * 4;  // wave owns global rows [row_lo, row_lo+4)
    int ylo = row_lo - 1; if (ylo < 0) ylo = 0;
    int yhi = row_lo + 4;         // <= 32 always

    float4* zl4 = (float4*)zl;
    float4 zero4 = make_float4(0.f, 0.f, 0.f, 0.f);
    for (int i = tid; i < 2048; i += 256) zl4[i] = zero4;
    __syncthreads();

    const int4* srt = sorted + (size_t)bh * NP;
    const float* vb = vsrc + (size_t)bh * NP * 16;
    const int* bsrt = bin_start + bh * 1024;
    int yzoff = dyb * 32 + dzb - row0 * 32;

#pragma unroll
    for (int pass = 0; pass < 2; ++pass) {
        int s = x - 1 + pass;      // pass0: dx=1 (slab x-1), pass1: dx=0 (slab x)
        if (s < 0 || s > 30) continue;
        int j0 = bsrt[s * 32 + ylo];
        int j1 = bsrt[s * 32 + yhi];
        bool dxh = (pass == 0);
        for (int j = j0; j < j1; j += 16) {
            // batch-load 16 records + 16 vals, unconditionally (clamped index);
            // in sorted mode the two load groups are independent -> 32 loads in flight
            int4 rec[16];
            float v[16];
#pragma unroll
            for (int u = 0; u < 16; ++u) {
                int jc = j + u; jc = (jc < NP - 1) ? jc : (NP - 1);
                rec[u] = srt[jc];
            }
#pragma unroll
            for (int u = 0; u < 16; ++u) {
                int jc = j + u; jc = (jc < NP - 1) ? jc : (NP - 1);
                int vidx = sortedVals ? jc : (rec[u].x & 4095);
                v[u] = vb[(size_t)vidx * 16 + ch];
            }
#pragma unroll
            for (int u = 0; u < 16; ++u) {
                int bs = rec[u].x >> 12;
                int r = ((bs >> 5) & 31) + dyb;            // target y row
                if (j + u < j1 && (unsigned)(r - row_lo) < 4u) {
                    float fx = __int_as_float(rec[u].y);
                    float fy = __int_as_float(rec[u].z);
                    float fz = __int_as_float(rec[u].w);
                    float w = (dxh ? fx : 1.f - fx) * (dyb ? fy : 1.f - fy) *
                              (dzb ? fz : 1.f - fz);
                    int addr = (bs & 1023) + yzoff;        // local (row,z) index
                    (&zl[0][0][0])[addr * 16 + ch] += w * v[u];   // non-atomic RMW
                }
            }
        }
    }
    __syncthreads();

    // write half-plane as bf16: 512 cells x 32B
    for (int i = tid; i < 1024; i += 256) {
        int cl = i >> 1, half = i & 1;
        float4 a = zl4[cl * 4 + half * 2];
        float4 c = zl4[cl * 4 + half * 2 + 1];
        uint4 o;
        o.x = f2bf(a.x) | (f2bf(a.y) << 16);
        o.y = f2bf(a.z) | (f2bf(a.w) << 16);
        o.z = f2bf(c.x) | (f2bf(c.y) << 16);
        o.w = f2bf(c.z) | (f2bf(c.w) << 16);
        int gcell = x * 1024 + row0 * 32 + cl;
        *(uint4*)&zout[((size_t)(bq * HH + h) * S3 + gcell) * 16 + half * 8] = o;
    }
}

// ---- grouped 3x3x3 conv via bf16 MFMA; z bf16 in, zc bf16 OUT -------------
__global__ __launch_bounds__(256) void k_conv(const unsigned short* __restrict__ z,
                                              const unsigned short* __restrict__ wApack,
                                              const float* __restrict__ cb,
                                              unsigned short* __restrict__ zc) {
    __shared__ __align__(16) unsigned short zl[4][10][34][16];   // 43,520 B
    int bx = blockIdx.x;      // 0..15 -> x pair
    int yq = blockIdx.y;      // 0..3  -> 8 y rows
    int gz = blockIdx.z;      // h + 8*bq
    int h  = gz & 7;
    int bq = gz >> 3;
    int tid = threadIdx.x;
    int lane = tid & 63, wid = tid >> 6;
    int x2 = bx * 2;

    const unsigned short* zb = z + (size_t)bq * ZSTRH;
    unsigned short* zcb = zc + (size_t)bq * ZSTRH;

    short8v af[14];
    const short8v* wa = (const short8v*)(wApack + (size_t)h * 14 * 64 * 8);
#pragma unroll
    for (int m = 0; m < 14; ++m) af[m] = wa[m * 64 + lane];

    for (int i = tid; i < 4 * 10 * 34; i += 256) {
        int dxi = i / 340, rem = i % 340;
        int yy = rem / 34, zi = rem % 34;
        int gx = x2 + dxi - 1, gy = yq * 8 + yy - 1, gzz = zi - 1;
        uint4* d4 = (uint4*)(&zl[0][0][0][0] + (size_t)i * 16);
        if (gx >= 0 && gx < SS && gy >= 0 && gy < SS && gzz >= 0 && gzz < SS) {
            const uint4* src = (const uint4*)&zb[((size_t)h * S3 +
                                 (gx * 1024 + gy * 32 + gzz)) * 16];
            d4[0] = src[0];
            d4[1] = src[1];
        } else {
            uint4 zz4 = make_uint4(0, 0, 0, 0);
            d4[0] = zz4; d4[1] = zz4;
        }
    }
    __syncthreads();

    bool lo = (lane & 32) == 0;
    int ci0 = (lane & 16) ? 8 : 0;
    int l15 = lane & 15;
    int fo0 = (lane >> 4) * 4;
    float4 bias = *(const float4*)&cb[h * 16 + fo0];
    const unsigned short* zlf = &zl[0][0][0][0];

#pragma unroll 1
    for (int i = 0; i < 8; ++i) {
        int gi = wid * 8 + i;
        int xl = gi >> 4, yl = (gi >> 1) & 7, zz0 = (gi & 1) * 16;
        int invbase = xl * 340 + yl * 34 + zz0 + l15;

        f32x4 acc = {0.f, 0.f, 0.f, 0.f};
#pragma unroll
        for (int m = 0; m < 14; ++m) {
            const int t0 = 2 * m;
            const int t1 = (2 * m + 1 > 26) ? 26 : (2 * m + 1);
            const int off0 = (t0 / 9) * 340 + ((t0 % 9) / 3) * 34 + (t0 % 3);
            const int off1 = (t1 / 9) * 340 + ((t1 % 9) / 3) * 34 + (t1 % 3);
            int offc = lo ? off0 : off1;
            const short8v* bp = (const short8v*)(zlf + (size_t)(invbase + offc) * 16 + ci0);
            acc = __builtin_amdgcn_mfma_f32_16x16x32_bf16(af[m], *bp, acc, 0, 0, 0);
        }
        int cell = (x2 + xl) * 1024 + (yq * 8 + yl) * 32 + zz0 + l15;
        uint2 o;
        o.x = f2bf(acc[0] + bias.x) | (f2bf(acc[1] + bias.y) << 16);
        o.y = f2bf(acc[2] + bias.z) | (f2bf(acc[3] + bias.w) << 16);
        *(uint2*)&zcb[((size_t)h * S3 + cell) * 16 + fo0] = o;
    }
}

// --- slice: thread per (point, fo-quad); zc bf16 [bq][h][cell][16] ---------
__global__ __launch_bounds__(256) void k_slice(const int* __restrict__ base,
                                               const float* __restrict__ frac,
                                               const unsigned short* __restrict__ zc,
                                               float* __restrict__ out, int b0) {
    int lid = blockIdx.x * 256 + threadIdx.x;
    int foq = blockIdx.y;
    int bq = blockIdx.z;
    int b = b0 + bq;
    int h = lid >> 12, n = lid & 4095;
    int gid = b * BPT + lid;
    int bs = base[gid];
    float fx = frac[gid], fy = frac[PTS + gid], fz = frac[2 * PTS + gid];
    float wx[2] = {1.f - fx, fx}, wy[2] = {1.f - fy, fy}, wz[2] = {1.f - fz, fz};
    const unsigned short* zb = zc + (size_t)bq * ZSTRH + (size_t)h * S3 * FF + foq * 4;

    float a0 = 0.f, a1 = 0.f, a2 = 0.f, a3 = 0.f;
#pragma unroll
    for (int dx = 0; dx < 2; ++dx)
#pragma unroll
    for (int dy = 0; dy < 2; ++dy)
#pragma unroll
    for (int dz = 0; dz < 2; ++dz) {
        int cell = bs + dx * (SS * SS) + dy * SS + dz;
        float w = wx[dx] * wy[dy] * wz[dz];
        uint2 u = *(const uint2*)&zb[(size_t)cell * FF];
        a0 = fmaf(__uint_as_float(u.x << 16), w, a0);
        a1 = fmaf(__uint_as_float(u.x & 0xffff0000u), w, a1);
        a2 = fmaf(__uint_as_float(u.y << 16), w, a2);
        a3 = fmaf(__uint_as_float(u.y & 0xffff0000u), w, a3);
    }
    size_t ob = ((size_t)b * (HH * FF) + h * FF + foq * 4) * NP + n;
    out[ob]          = a0;
    out[ob + NP]     = a1;
    out[ob + 2 * NP] = a2;
    out[ob + 3 * NP] = a3;
}

// ------------- BN stats over (B,N) for the 128 sliced channels -------------
__global__ __launch_bounds__(256) void k_stats2(const float* __restrict__ out,
                                                const float* __restrict__ ag,
                                                const float* __restrict__ ab,
                                                float* __restrict__ A2,
                                                float* __restrict__ B2) {
    int c = blockIdx.x, tid = threadIdx.x;
    float s = 0.f, ss = 0.f;
    for (int b = 0; b < BB; ++b) {
        const float* p = out + ((size_t)b * (HH * FF) + c) * NP;
        for (int n = tid; n < NP; n += 256) { float v = p[n]; s += v; ss = fmaf(v, v, ss); }
    }
#pragma unroll
    for (int off = 32; off > 0; off >>= 1) { s += __shfl_down(s, off); ss += __shfl_down(ss, off); }
    __shared__ float sh[8];
    int lane = tid & 63, w = tid >> 6;
    if (lane == 0) { sh[w] = s; sh[4 + w] = ss; }
    __syncthreads();
    if (tid == 0) {
        float S_ = sh[0] + sh[1] + sh[2] + sh[3];
        float SSv = sh[4] + sh[5] + sh[6] + sh[7];
        float mean = S_ * (1.f / BN_CNT);
        float var  = SSv * (1.f / BN_CNT) - mean * mean;
        float rstd = rsqrtf(var + EPSV);
        A2[c] = rstd * ag[c];
        B2[c] = ab[c] - mean * rstd * ag[c];
    }
}

// ---------------- final BN + ReLU in-place on d_out ------------------------
__global__ __launch_bounds__(256) void k_bnrelu(float* __restrict__ out,
                                                const float* __restrict__ A2,
                                                const float* __restrict__ B2) {
    int gid = blockIdx.x * 256 + threadIdx.x;
    int c = (gid >> 12) & 127;
    float v = out[gid];
    out[gid] = fmaxf(fmaf(A2[c], v, B2[c]), 0.f);
}

// ---------------------------------------------------------------------------
extern "C" void kernel_launch(void* const* d_in, const int* in_sizes, int n_in,
                              void* d_out, int out_size, void* d_ws, size_t ws_size,
                              hipStream_t stream) {
    (void)in_sizes; (void)n_in; (void)out_size;
    const float* x   = (const float*)d_in[0];
    const float* pcd = (const float*)d_in[1];
    const float* W   = (const float*)d_in[2];
    const float* kg  = (const float*)d_in[3];
    const float* kb  = (const float*)d_in[4];
    const float* vg  = (const float*)d_in[5];
    const float* vb  = (const float*)d_in[6];
    const float* R   = (const float*)d_in[7];
    const float* t   = (const float*)d_in[8];
    const float* cw  = (const float*)d_in[9];
    const float* cb  = (const float*)d_in[10];
    const float* ag  = (const float*)d_in[11];
    const float* ab  = (const float*)d_in[12];
    float* out = (float*)d_out;
    char* ws = (char*)d_ws;

    float* kv   = (float*)(ws + 0);            // 19,922,944; dead after k_prep
    int4*  sorted    = (int4*)(ws + 8388608ULL);   // 4 MB
    int*   bin_start = (int*) (ws + 12582912ULL);  // 256 KB
    unsigned short* wApack = (unsigned short*)(ws + 16777216ULL);
    int*   base = (int*)  (ws + 19922944ULL);
    float* frac = (float*)(ws + 20971520ULL);
    float* A    = (float*)(ws + 24117248ULL);
    float* Bv   = (float*)(ws + 24118272ULL);
    float* A2   = (float*)(ws + 24119296ULL);
    float* B2   = (float*)(ws + 24120320ULL);
    float* vals = (float*)(ws + 24121344ULL);  // 16,777,216 [point][16]

    // per-batch: z_bf 8 MB + zc(bf16) 8 MB = 16 MB; + vals_s 16.7 MB
    int NB = 1;
    if (ws_size >= 40898560ULL + 8ULL * 16777216ULL + 16777216ULL)      NB = 8;  // 191,889,408
    else if (ws_size >= 40898560ULL + 4ULL * 16777216ULL + 16777216ULL) NB = 4;
    else if (ws_size >= 40898560ULL + 2ULL * 16777216ULL + 16777216ULL) NB = 2;

    unsigned short* z_bf;
    unsigned short* zc;
    float* vals_s = nullptr;
    int sortedVals = 1;
    if (NB == 1) {
        z_bf = (unsigned short*)kv;
        zc   = (unsigned short*)(ws + 40898560ULL);
        if (ws_size >= 57675776ULL + 16777216ULL)
            vals_s = (float*)(ws + 57675776ULL);
        else { vals_s = vals; sortedVals = 0; }
    } else {
        z_bf = (unsigned short*)(ws + 40898560ULL);                   // NB * 8 MB
        zc   = (unsigned short*)(ws + 40898560ULL + (size_t)NB * 8388608ULL);  // NB * 8 MB
        vals_s = (float*)(ws + 40898560ULL + (size_t)NB * 16777216ULL);
    }
    // GEMM W-pack (160 KB, hi+lo) aliases the zc region: written before
    // k_gemm, read only by k_gemm, clobbered later by k_conv.
    unsigned short* wg = (unsigned short*)zc;

    k_wgpack<<<dim3(20), 256, 0, stream>>>(W, wg);
    k_gemm<<<dim3(64, BB), 256, 0, stream>>>(x, wg, kv);
    k_stats_kv<<<dim3(CC), 256, 0, stream>>>(kv, kg, kb, vg, vb, A, Bv);
    k_prep<<<dim3(PTS / 256), 256, 0, stream>>>(kv, pcd, A, Bv, R, t, base, frac, vals);
    k_bin<<<dim3(BB * HH), 256, 0, stream>>>(base, frac, sorted, bin_start);
    if (sortedVals)
        k_vperm<<<dim3(PTS * 4 / 256), 256, 0, stream>>>(sorted, vals, vals_s);
    k_wpack<<<dim3(28), 256, 0, stream>>>(cw, wApack);

    for (int b0 = 0; b0 < BB; b0 += NB) {
        k_splat<<<dim3(SS, 2, HH * NB), 256, 0, stream>>>(sorted, bin_start, vals_s,
                                                          z_bf, b0, sortedVals);
        k_conv<<<dim3(16, 4, HH * NB), 256, 0, stream>>>(z_bf, wApack, cb, zc);
        k_slice<<<dim3(BPT / 256, 4, NB), 256, 0, stream>>>(base, frac, zc, out, b0);
    }

    k_stats2<<<dim3(HH * FF), 256, 0, stream>>>(out, ag, ab, A2, B2);
    k_bnrelu<<<dim3((BB * HH * FF * NP) / 256), 256, 0, stream>>>(out, A2, B2);
}

// Round 19
// 315.360 us; speedup vs baseline: 1.0705x; 1.0705x over previous
//
#include <hip/hip_runtime.h>
#include <cstddef>
#include <cstdint>

#define BB 8
#define MD 256
#define NP 4096
#define HH 8
#define FF 16
#define SS 32
#define S3 32768
#define CC 152      // H*(F+3)
#define KC 24       // H*3
#define PTS (BB*HH*NP)   // 262144
#define BPT (HH*NP)      // points per batch = 32768
#define BN_CNT (BB*NP)   // 32768
#define EPSV 1e-5f
#define ZSTRH (HH*S3*FF)     // per-batch lattice ushorts (bf16) = 4,194,304 (8 MB)

typedef __attribute__((ext_vector_type(8))) short short8v;
typedef __attribute__((ext_vector_type(4))) float f32x4;

__device__ __forceinline__ unsigned int f2bf(float f) {
    unsigned int u = __float_as_uint(f);
    unsigned int r = u + 0x7FFFu + ((u >> 16) & 1u);   // round-to-nearest-even
    return r >> 16;
}

// ---- pack W_kv into MFMA A-frag lane order, SPLIT bf16 (hi + lo) ----------
__global__ __launch_bounds__(256) void k_wgpack(const float* __restrict__ W,
                                                unsigned short* __restrict__ wg) {
    int gid = blockIdx.x * 256 + threadIdx.x;     // 10*8*64 = 5120
    if (gid >= 5120) return;
    int lane = gid & 63;
    int mc   = (gid >> 6) & 7;
    int oct  = gid >> 9;
    int oc = oct * 16 + (lane & 15);
    int m0 = mc * 32 + (lane >> 4) * 8;
    unsigned short oh[8], ol[8];
#pragma unroll
    for (int j = 0; j < 8; ++j) {
        float wv = (oc < CC) ? W[(size_t)oc * MD + m0 + j] : 0.f;
        unsigned int hi = f2bf(wv);
        float r = wv - __uint_as_float(hi << 16);
        oh[j] = (unsigned short)hi;
        ol[j] = (unsigned short)f2bf(r);
    }
    ushort4* dh = (ushort4*)(wg + (size_t)gid * 8);
    dh[0] = make_ushort4(oh[0], oh[1], oh[2], oh[3]);
    dh[1] = make_ushort4(oh[4], oh[5], oh[6], oh[7]);
    ushort4* dl = (ushort4*)(wg + (size_t)(5120 + gid) * 8);
    dl[0] = make_ushort4(ol[0], ol[1], ol[2], ol[3]);
    dl[1] = make_ushort4(ol[4], ol[5], ol[6], ol[7]);
}

// ------ GEMM via split-bf16 MFMA: kv = W x, near-fp32 accurate -------------
__global__ __launch_bounds__(256) void k_gemm(const float* __restrict__ x,
                                              const unsigned short* __restrict__ wg,
                                              float* __restrict__ kv) {
    __shared__ __align__(16) unsigned char xh[32768];    // [64 n][256 m] bf16 swz
    __shared__ __align__(16) unsigned char xlo[32768];
    int nt = blockIdx.x;          // 0..63
    int b  = blockIdx.y;
    int tid = threadIdx.x;
    int n_l = tid & 63, w = tid >> 6;
    int n0 = nt * 64;

    const float* xb = x + (size_t)b * MD * NP + n0;
#pragma unroll 4
    for (int k = 0; k < 32; ++k) {
        int m = k * 8 + w * 2;
        float v0 = xb[(size_t)m * NP + n_l];
        float v1 = xb[(size_t)(m + 1) * NP + n_l];
        unsigned int h0 = f2bf(v0), h1 = f2bf(v1);
        float r0 = v0 - __uint_as_float(h0 << 16);
        float r1 = v1 - __uint_as_float(h1 << 16);
        unsigned int byte = (unsigned)(n_l * 512 + m * 2) ^ (unsigned)((n_l & 7) << 4);
        *(unsigned int*)(xh + byte)  = h0 | (h1 << 16);
        *(unsigned int*)(xlo + byte) = f2bf(r0) | (f2bf(r1) << 16);
    }
    __syncthreads();

    int lane = tid & 63;
    int nn = w * 16 + (lane & 15);
    int kg = lane >> 4;
    short8v xfh[8], xfl[8];
#pragma unroll
    for (int mc = 0; mc < 8; ++mc) {
        unsigned int byte = (unsigned)(nn * 512 + (mc * 32 + kg * 8) * 2)
                          ^ (unsigned)((nn & 7) << 4);
        xfh[mc] = *(const short8v*)(xh + byte);
        xfl[mc] = *(const short8v*)(xlo + byte);
    }

    f32x4 acc[10];
#pragma unroll
    for (int t = 0; t < 10; ++t) acc[t] = (f32x4){0.f, 0.f, 0.f, 0.f};

    const short8v* wfh = (const short8v*)wg;
    const short8v* wfl = wfh + 5120;
#pragma unroll
    for (int oct = 0; oct < 10; ++oct) {
#pragma unroll
        for (int mc = 0; mc < 8; ++mc) {
            short8v wh = wfh[(oct * 8 + mc) * 64 + lane];
            short8v wl = wfl[(oct * 8 + mc) * 64 + lane];
            acc[oct] = __builtin_amdgcn_mfma_f32_16x16x32_bf16(wh, xfh[mc], acc[oct], 0, 0, 0);
            acc[oct] = __builtin_amdgcn_mfma_f32_16x16x32_bf16(wh, xfl[mc], acc[oct], 0, 0, 0);
            acc[oct] = __builtin_amdgcn_mfma_f32_16x16x32_bf16(wl, xfh[mc], acc[oct], 0, 0, 0);
        }
    }

    int n = n0 + nn;
#pragma unroll
    for (int oct = 0; oct < 10; ++oct) {
#pragma unroll
        for (int r = 0; r < 4; ++r) {
            int oc = oct * 16 + kg * 4 + r;
            if (oc < CC)
                kv[((size_t)b * CC + oc) * NP + n] = acc[oct][r];
        }
    }
}

// ------------- BN stats over (B,N) for all 152 kv channels -----------------
__global__ __launch_bounds__(256) void k_stats_kv(const float* __restrict__ kv,
                                                  const float* __restrict__ kg,
                                                  const float* __restrict__ kb,
                                                  const float* __restrict__ vg,
                                                  const float* __restrict__ vb,
                                                  float* __restrict__ A,
                                                  float* __restrict__ Bv) {
    int o = blockIdx.x, tid = threadIdx.x;
    float s = 0.f, ss = 0.f;
    for (int b = 0; b < BB; ++b) {
        const float* p = kv + ((size_t)b * CC + o) * NP;
        for (int n = tid; n < NP; n += 256) { float v = p[n]; s += v; ss = fmaf(v, v, ss); }
    }
#pragma unroll
    for (int off = 32; off > 0; off >>= 1) { s += __shfl_down(s, off); ss += __shfl_down(ss, off); }
    __shared__ float sh[8];
    int lane = tid & 63, w = tid >> 6;
    if (lane == 0) { sh[w] = s; sh[4 + w] = ss; }
    __syncthreads();
    if (tid == 0) {
        float S_ = sh[0] + sh[1] + sh[2] + sh[3];
        float SSv = sh[4] + sh[5] + sh[6] + sh[7];
        float mean = S_ * (1.f / BN_CNT);
        float var  = SSv * (1.f / BN_CNT) - mean * mean;
        float rstd = rsqrtf(var + EPSV);
        float g  = (o < KC) ? kg[o] : vg[o - KC];
        float be = (o < KC) ? kb[o] : vb[o - KC];
        A[o]  = rstd * g;
        Bv[o] = be - mean * rstd * g;
    }
}

// --- per-point: BN keys -> affine -> tanh -> idx/frac; also emit vals[.,16] -
__global__ __launch_bounds__(256) void k_prep(const float* __restrict__ kv,
                                              const float* __restrict__ pcd,
                                              const float* __restrict__ A,
                                              const float* __restrict__ Bv,
                                              const float* __restrict__ R,
                                              const float* __restrict__ t,
                                              int* __restrict__ base,
                                              float* __restrict__ frac,
                                              float* __restrict__ vals) {
    int gid = blockIdx.x * 256 + threadIdx.x;
    int b = gid >> 15, h = (gid >> 12) & 7, n = gid & 4095;

    float p[3];
#pragma unroll
    for (int i = 0; i < 3; ++i) {
        int c = h * 3 + i;
        float v = kv[((size_t)b * CC + c) * NP + n];
        p[i] = pcd[((size_t)b * 3 + i) * NP + n] + fmaf(A[c], v, Bv[c]);
    }
    int fl[3]; float fr[3];
#pragma unroll
    for (int i = 0; i < 3; ++i) {
        float key = R[h * 9 + i * 3 + 0] * p[0] + R[h * 9 + i * 3 + 1] * p[1] +
                    R[h * 9 + i * 3 + 2] * p[2] + t[h * 3 + i];
        float lat = tanhf(key);
        float pos = (lat + 1.f) * 0.5f * (SS - 1);
        float flf = fminf(fmaxf(floorf(pos), 0.f), (float)(SS - 2));
        fr[i] = pos - flf;
        fl[i] = (int)flf;
    }
    base[gid] = (fl[0] * SS + fl[1]) * SS + fl[2];
    frac[gid]           = fr[0];
    frac[PTS + gid]     = fr[1];
    frac[2 * PTS + gid] = fr[2];

    float4* vo = (float4*)(vals + (size_t)gid * 16);
#pragma unroll
    for (int q = 0; q < 4; ++q) {
        float4 v;
        float* vv = (float*)&v;
#pragma unroll
        for (int j = 0; j < 4; ++j) {
            int c = KC + h * FF + q * 4 + j;
            vv[j] = fmaf(A[c], kv[((size_t)b * CC + c) * NP + n], Bv[c]);
        }
        vo[q] = v;
    }
}

// ---- counting sort per (b,h): 1024 (slab,y) bins -> sorted records --------
__global__ __launch_bounds__(256) void k_bin(const int* __restrict__ base,
                                             const float* __restrict__ frac,
                                             int4* __restrict__ sorted,
                                             int* __restrict__ bin_start) {
    __shared__ int hist[1024];
    __shared__ int curs[1024];
    int bh = blockIdx.x;           // b*8+h  (gid = bh*NP + n)
    int tid = threadIdx.x;
    for (int k = tid; k < 1024; k += 256) hist[k] = 0;
    __syncthreads();
    int gb = bh * NP;
    for (int p = tid; p < NP; p += 256)
        atomicAdd(&hist[base[gb + p] >> 5], 1);
    __syncthreads();
    if (tid == 0) {
        int run = 0;
        for (int k = 0; k < 1024; ++k) { int c = hist[k]; hist[k] = run; run += c; }
    }
    __syncthreads();
    for (int k = tid; k < 1024; k += 256) {
        bin_start[bh * 1024 + k] = hist[k];
        curs[k] = hist[k];
    }
    __syncthreads();
    for (int p = tid; p < NP; p += 256) {
        int bs = base[gb + p];
        int slot = atomicAdd(&curs[bs >> 5], 1);
        sorted[(size_t)bh * NP + slot] =
            make_int4(p | (bs << 12),
                      __float_as_int(frac[gb + p]),
                      __float_as_int(frac[PTS + gb + p]),
                      __float_as_int(frac[2 * PTS + gb + p]));
    }
}

// ---- permute vals into sorted-bin order: vals_s[j] = vals[sorted[j].p] ----
__global__ __launch_bounds__(256) void k_vperm(const int4* __restrict__ sorted,
                                               const float* __restrict__ vals,
                                               float* __restrict__ vals_s) {
    int gid = blockIdx.x * 256 + threadIdx.x;    // over PTS*4 quads
    int j = gid >> 2, q = gid & 3;
    int bh = j >> 12;
    int p = sorted[j].x & 4095;
    float4 v = ((const float4*)(vals + ((size_t)bh * NP + p) * 16))[q];
    ((float4*)(vals_s + (size_t)j * 16))[q] = v;
}

// ---- pack conv weights into MFMA A-fragment lane order (bf16) -------------
__global__ __launch_bounds__(256) void k_wpack(const float* __restrict__ cw,
                                               unsigned short* __restrict__ wApack) {
    int gid = blockIdx.x * 256 + threadIdx.x;     // (h*14 + m)*64 + lane
    if (gid >= 8 * 14 * 64) return;
    int lane = gid & 63;
    int m = (gid >> 6) % 14;
    int h = gid / (14 * 64);
    int fo = lane & 15, g = lane >> 4;
    int tap = 2 * m + (g >> 1);
    int ci0 = (g & 1) * 8;
    unsigned short o[8];
#pragma unroll
    for (int j = 0; j < 8; ++j) {
        float w = (tap <= 26) ? cw[((size_t)(h * 16 + fo) * 16 + ci0 + j) * 27 + tap] : 0.f;
        o[j] = (unsigned short)f2bf(w);
    }
    ushort4* dst = (ushort4*)(wApack + (size_t)gid * 8);
    dst[0] = make_ushort4(o[0], o[1], o[2], o[3]);
    dst[1] = make_ushort4(o[4], o[5], o[6], o[7]);
}

// --- splat: SINGLE-WAVE blocks (x, y-quarter, h, bq); 64 thr, 8 KB LDS -----
// Wave owns rows [4*yq, 4*yq+4); 8-record batched predicated loads;
// no LDS atomics; (slab,y)-sorted bins give a contiguous y-window scan.
__global__ __launch_bounds__(64) void k_splat(const int4* __restrict__ sorted,
                                              const int* __restrict__ bin_start,
                                              const float* __restrict__ vsrc,
                                              unsigned short* __restrict__ zout,
                                              int b0, int sortedVals) {
    __shared__ float zl[4][32][16];          // 8 KB fp32 accumulate
    int x  = blockIdx.x;          // 0..31 output plane
    int yq = blockIdx.y;          // 0..7  y quarter
    int hq = blockIdx.z;          // h + 8*bq
    int h = hq & 7, bq = hq >> 3;
    int bh = (b0 + bq) * 8 + h;
    int lane = threadIdx.x;       // 0..63
    int ch = lane & 15, cor = lane >> 4;
    int dyb = cor >> 1, dzb = cor & 1;
    int row_lo = yq * 4;          // wave owns global rows [row_lo, row_lo+4)
    int ylo = row_lo - 1; if (ylo < 0) ylo = 0;
    int yhi = row_lo + 4;         // <= 32 always

    float4* zl4 = (float4*)zl;
    float4 zero4 = make_float4(0.f, 0.f, 0.f, 0.f);
    for (int i = lane; i < 512; i += 64) zl4[i] = zero4;
    __syncthreads();

    const int4* srt = sorted + (size_t)bh * NP;
    const float* vb = vsrc + (size_t)bh * NP * 16;
    const int* bsrt = bin_start + bh * 1024;
    int yzoff = dyb * 32 + dzb - row_lo * 32;

#pragma unroll
    for (int pass = 0; pass < 2; ++pass) {
        int s = x - 1 + pass;      // pass0: dx=1 (slab x-1), pass1: dx=0 (slab x)
        if (s < 0 || s > 30) continue;
        int j0 = bsrt[s * 32 + ylo];
        int j1 = bsrt[s * 32 + yhi];
        bool dxh = (pass == 0);
        for (int j = j0; j < j1; j += 8) {
            int4 rec[8];
            float v[8];
#pragma unroll
            for (int u = 0; u < 8; ++u) {
                int jc = j + u; jc = (jc < NP - 1) ? jc : (NP - 1);
                rec[u] = srt[jc];
            }
#pragma unroll
            for (int u = 0; u < 8; ++u) {
                int jc = j + u; jc = (jc < NP - 1) ? jc : (NP - 1);
                int vidx = sortedVals ? jc : (rec[u].x & 4095);
                v[u] = vb[(size_t)vidx * 16 + ch];
            }
#pragma unroll
            for (int u = 0; u < 8; ++u) {
                int bs = rec[u].x >> 12;
                int r = ((bs >> 5) & 31) + dyb;            // target y row
                if (j + u < j1 && (unsigned)(r - row_lo) < 4u) {
                    float fx = __int_as_float(rec[u].y);
                    float fy = __int_as_float(rec[u].z);
                    float fz = __int_as_float(rec[u].w);
                    float w = (dxh ? fx : 1.f - fx) * (dyb ? fy : 1.f - fy) *
                              (dzb ? fz : 1.f - fz);
                    int addr = (bs & 1023) + yzoff;        // local (row,z) index
                    (&zl[0][0][0])[addr * 16 + ch] += w * v[u];   // non-atomic RMW
                }
            }
        }
    }
    __syncthreads();

    // write quarter-plane as bf16: 128 cells x 32B
    for (int i = lane; i < 256; i += 64) {
        int cl = i >> 1, half = i & 1;
        float4 a = zl4[cl * 4 + half * 2];
        float4 c = zl4[cl * 4 + half * 2 + 1];
        uint4 o;
        o.x = f2bf(a.x) | (f2bf(a.y) << 16);
        o.y = f2bf(a.z) | (f2bf(a.w) << 16);
        o.z = f2bf(c.x) | (f2bf(c.y) << 16);
        o.w = f2bf(c.z) | (f2bf(c.w) << 16);
        int gcell = x * 1024 + row_lo * 32 + cl;
        *(uint4*)&zout[((size_t)(bq * HH + h) * S3 + gcell) * 16 + half * 8] = o;
    }
}

// ---- grouped 3x3x3 conv via bf16 MFMA; z bf16 in, zc bf16 OUT -------------
__global__ __launch_bounds__(256) void k_conv(const unsigned short* __restrict__ z,
                                              const unsigned short* __restrict__ wApack,
                                              const float* __restrict__ cb,
                                              unsigned short* __restrict__ zc) {
    __shared__ __align__(16) unsigned short zl[4][10][34][16];   // 43,520 B
    int bx = blockIdx.x;      // 0..15 -> x pair
    int yq = blockIdx.y;      // 0..3  -> 8 y rows
    int gz = blockIdx.z;      // h + 8*bq
    int h  = gz & 7;
    int bq = gz >> 3;
    int tid = threadIdx.x;
    int lane = tid & 63, wid = tid >> 6;
    int x2 = bx * 2;

    const unsigned short* zb = z + (size_t)bq * ZSTRH;
    unsigned short* zcb = zc + (size_t)bq * ZSTRH;

    short8v af[14];
    const short8v* wa = (const short8v*)(wApack + (size_t)h * 14 * 64 * 8);
#pragma unroll
    for (int m = 0; m < 14; ++m) af[m] = wa[m * 64 + lane];

    for (int i = tid; i < 4 * 10 * 34; i += 256) {
        int dxi = i / 340, rem = i % 340;
        int yy = rem / 34, zi = rem % 34;
        int gx = x2 + dxi - 1, gy = yq * 8 + yy - 1, gzz = zi - 1;
        uint4* d4 = (uint4*)(&zl[0][0][0][0] + (size_t)i * 16);
        if (gx >= 0 && gx < SS && gy >= 0 && gy < SS && gzz >= 0 && gzz < SS) {
            const uint4* src = (const uint4*)&zb[((size_t)h * S3 +
                                 (gx * 1024 + gy * 32 + gzz)) * 16];
            d4[0] = src[0];
            d4[1] = src[1];
        } else {
            uint4 zz4 = make_uint4(0, 0, 0, 0);
            d4[0] = zz4; d4[1] = zz4;
        }
    }
    __syncthreads();

    bool lo = (lane & 32) == 0;
    int ci0 = (lane & 16) ? 8 : 0;
    int l15 = lane & 15;
    int fo0 = (lane >> 4) * 4;
    float4 bias = *(const float4*)&cb[h * 16 + fo0];
    const unsigned short* zlf = &zl[0][0][0][0];

#pragma unroll 1
    for (int i = 0; i < 8; ++i) {
        int gi = wid * 8 + i;
        int xl = gi >> 4, yl = (gi >> 1) & 7, zz0 = (gi & 1) * 16;
        int invbase = xl * 340 + yl * 34 + zz0 + l15;

        f32x4 acc = {0.f, 0.f, 0.f, 0.f};
#pragma unroll
        for (int m = 0; m < 14; ++m) {
            const int t0 = 2 * m;
            const int t1 = (2 * m + 1 > 26) ? 26 : (2 * m + 1);
            const int off0 = (t0 / 9) * 340 + ((t0 % 9) / 3) * 34 + (t0 % 3);
            const int off1 = (t1 / 9) * 340 + ((t1 % 9) / 3) * 34 + (t1 % 3);
            int offc = lo ? off0 : off1;
            const short8v* bp = (const short8v*)(zlf + (size_t)(invbase + offc) * 16 + ci0);
            acc = __builtin_amdgcn_mfma_f32_16x16x32_bf16(af[m], *bp, acc, 0, 0, 0);
        }
        int cell = (x2 + xl) * 1024 + (yq * 8 + yl) * 32 + zz0 + l15;
        uint2 o;
        o.x = f2bf(acc[0] + bias.x) | (f2bf(acc[1] + bias.y) << 16);
        o.y = f2bf(acc[2] + bias.z) | (f2bf(acc[3] + bias.w) << 16);
        *(uint2*)&zcb[((size_t)h * S3 + cell) * 16 + fo0] = o;
    }
}

// --- slice: thread per (point, fo-quad); zc bf16 [bq][h][cell][16] ---------
__global__ __launch_bounds__(256) void k_slice(const int* __restrict__ base,
                                               const float* __restrict__ frac,
                                               const unsigned short* __restrict__ zc,
                                               float* __restrict__ out, int b0) {
    int lid = blockIdx.x * 256 + threadIdx.x;
    int foq = blockIdx.y;
    int bq = blockIdx.z;
    int b = b0 + bq;
    int h = lid >> 12, n = lid & 4095;
    int gid = b * BPT + lid;
    int bs = base[gid];
    float fx = frac[gid], fy = frac[PTS + gid], fz = frac[2 * PTS + gid];
    float wx[2] = {1.f - fx, fx}, wy[2] = {1.f - fy, fy}, wz[2] = {1.f - fz, fz};
    const unsigned short* zb = zc + (size_t)bq * ZSTRH + (size_t)h * S3 * FF + foq * 4;

    float a0 = 0.f, a1 = 0.f, a2 = 0.f, a3 = 0.f;
#pragma unroll
    for (int dx = 0; dx < 2; ++dx)
#pragma unroll
    for (int dy = 0; dy < 2; ++dy)
#pragma unroll
    for (int dz = 0; dz < 2; ++dz) {
        int cell = bs + dx * (SS * SS) + dy * SS + dz;
        float w = wx[dx] * wy[dy] * wz[dz];
        uint2 u = *(const uint2*)&zb[(size_t)cell * FF];
        a0 = fmaf(__uint_as_float(u.x << 16), w, a0);
        a1 = fmaf(__uint_as_float(u.x & 0xffff0000u), w, a1);
        a2 = fmaf(__uint_as_float(u.y << 16), w, a2);
        a3 = fmaf(__uint_as_float(u.y & 0xffff0000u), w, a3);
    }
    size_t ob = ((size_t)b * (HH * FF) + h * FF + foq * 4) * NP + n;
    out[ob]          = a0;
    out[ob + NP]     = a1;
    out[ob + 2 * NP] = a2;
    out[ob + 3 * NP] = a3;
}

// ------------- BN stats over (B,N) for the 128 sliced channels -------------
__global__ __launch_bounds__(256) void k_stats2(const float* __restrict__ out,
                                                const float* __restrict__ ag,
                                                const float* __restrict__ ab,
                                                float* __restrict__ A2,
                                                float* __restrict__ B2) {
    int c = blockIdx.x, tid = threadIdx.x;
    float s = 0.f, ss = 0.f;
    for (int b = 0; b < BB; ++b) {
        const float* p = out + ((size_t)b * (HH * FF) + c) * NP;
        for (int n = tid; n < NP; n += 256) { float v = p[n]; s += v; ss = fmaf(v, v, ss); }
    }
#pragma unroll
    for (int off = 32; off > 0; off >>= 1) { s += __shfl_down(s, off); ss += __shfl_down(ss, off); }
    __shared__ float sh[8];
    int lane = tid & 63, w = tid >> 6;
    if (lane == 0) { sh[w] = s; sh[4 + w] = ss; }
    __syncthreads();
    if (tid == 0) {
        float S_ = sh[0] + sh[1] + sh[2] + sh[3];
        float SSv = sh[4] + sh[5] + sh[6] + sh[7];
        float mean = S_ * (1.f / BN_CNT);
        float var  = SSv * (1.f / BN_CNT) - mean * mean;
        float rstd = rsqrtf(var + EPSV);
        A2[c] = rstd * ag[c];
        B2[c] = ab[c] - mean * rstd * ag[c];
    }
}

// ---------------- final BN + ReLU in-place on d_out ------------------------
__global__ __launch_bounds__(256) void k_bnrelu(float* __restrict__ out,
                                                const float* __restrict__ A2,
                                                const float* __restrict__ B2) {
    int gid = blockIdx.x * 256 + threadIdx.x;
    int c = (gid >> 12) & 127;
    float v = out[gid];
    out[gid] = fmaxf(fmaf(A2[c], v, B2[c]), 0.f);
}

// ---------------------------------------------------------------------------
extern "C" void kernel_launch(void* const* d_in, const int* in_sizes, int n_in,
                              void* d_out, int out_size, void* d_ws, size_t ws_size,
                              hipStream_t stream) {
    (void)in_sizes; (void)n_in; (void)out_size;
    const float* x   = (const float*)d_in[0];
    const float* pcd = (const float*)d_in[1];
    const float* W   = (const float*)d_in[2];
    const float* kg  = (const float*)d_in[3];
    const float* kb  = (const float*)d_in[4];
    const float* vg  = (const float*)d_in[5];
    const float* vb  = (const float*)d_in[6];
    const float* R   = (const float*)d_in[7];
    const float* t   = (const float*)d_in[8];
    const float* cw  = (const float*)d_in[9];
    const float* cb  = (const float*)d_in[10];
    const float* ag  = (const float*)d_in[11];
    const float* ab  = (const float*)d_in[12];
    float* out = (float*)d_out;
    char* ws = (char*)d_ws;

    float* kv   = (float*)(ws + 0);            // 19,922,944; dead after k_prep
    int4*  sorted    = (int4*)(ws + 8388608ULL);   // 4 MB
    int*   bin_start = (int*) (ws + 12582912ULL);  // 256 KB
    unsigned short* wApack = (unsigned short*)(ws + 16777216ULL);
    int*   base = (int*)  (ws + 19922944ULL);
    float* frac = (float*)(ws + 20971520ULL);
    float* A    = (float*)(ws + 24117248ULL);
    float* Bv   = (float*)(ws + 24118272ULL);
    float* A2   = (float*)(ws + 24119296ULL);
    float* B2   = (float*)(ws + 24120320ULL);
    float* vals = (float*)(ws + 24121344ULL);  // 16,777,216 [point][16]

    // per-batch: z_bf 8 MB + zc(bf16) 8 MB = 16 MB; + vals_s 16.7 MB
    int NB = 1;
    if (ws_size >= 40898560ULL + 8ULL * 16777216ULL + 16777216ULL)      NB = 8;  // 191,889,408
    else if (ws_size >= 40898560ULL + 4ULL * 16777216ULL + 16777216ULL) NB = 4;
    else if (ws_size >= 40898560ULL + 2ULL * 16777216ULL + 16777216ULL) NB = 2;

    unsigned short* z_bf;
    unsigned short* zc;
    float* vals_s = nullptr;
    int sortedVals = 1;
    if (NB == 1) {
        z_bf = (unsigned short*)kv;
        zc   = (unsigned short*)(ws + 40898560ULL);
        if (ws_size >= 57675776ULL + 16777216ULL)
            vals_s = (float*)(ws + 57675776ULL);
        else { vals_s = vals; sortedVals = 0; }
    } else {
        z_bf = (unsigned short*)(ws + 40898560ULL);                   // NB * 8 MB
        zc   = (unsigned short*)(ws + 40898560ULL + (size_t)NB * 8388608ULL);  // NB * 8 MB
        vals_s = (float*)(ws + 40898560ULL + (size_t)NB * 16777216ULL);
    }
    // GEMM W-pack (160 KB, hi+lo) aliases the zc region: written before
    // k_gemm, read only by k_gemm, clobbered later by k_conv.
    unsigned short* wg = (unsigned short*)zc;

    k_wgpack<<<dim3(20), 256, 0, stream>>>(W, wg);
    k_gemm<<<dim3(64, BB), 256, 0, stream>>>(x, wg, kv);
    k_stats_kv<<<dim3(CC), 256, 0, stream>>>(kv, kg, kb, vg, vb, A, Bv);
    k_prep<<<dim3(PTS / 256), 256, 0, stream>>>(kv, pcd, A, Bv, R, t, base, frac, vals);
    k_bin<<<dim3(BB * HH), 256, 0, stream>>>(base, frac, sorted, bin_start);
    if (sortedVals)
        k_vperm<<<dim3(PTS * 4 / 256), 256, 0, stream>>>(sorted, vals, vals_s);
    k_wpack<<<dim3(28), 256, 0, stream>>>(cw, wApack);

    for (int b0 = 0; b0 < BB; b0 += NB) {
        k_splat<<<dim3(SS, 8, HH * NB), 64, 0, stream>>>(sorted, bin_start, vals_s,
                                                         z_bf, b0, sortedVals);
        k_conv<<<dim3(16, 4, HH * NB), 256, 0, stream>>>(z_bf, wApack, cb, zc);
        k_slice<<<dim3(BPT / 256, 4, NB), 256, 0, stream>>>(base, frac, zc, out, b0);
    }

    k_stats2<<<dim3(HH * FF), 256, 0, stream>>>(out, ag, ab, A2, B2);
    k_bnrelu<<<dim3((BB * HH * FF * NP) / 256), 256, 0, stream>>>(out, A2, B2);
}

// Round 20
// 303.593 us; speedup vs baseline: 1.1120x; 1.0388x over previous
//
#include <hip/hip_runtime.h>
#include <cstddef>
#include <cstdint>

#define BB 8
#define MD 256
#define NP 4096
#define HH 8
#define FF 16
#define SS 32
#define S3 32768
#define CC 152      // H*(F+3)
#define KC 24       // H*3
#define PTS (BB*HH*NP)   // 262144
#define BPT (HH*NP)      // points per batch = 32768
#define BN_CNT (BB*NP)   // 32768
#define EPSV 1e-5f
#define ZSTRH (HH*S3*FF)     // per-batch lattice ushorts (bf16) = 4,194,304 (8 MB)

typedef __attribute__((ext_vector_type(8))) short short8v;
typedef __attribute__((ext_vector_type(4))) float f32x4;

__device__ __forceinline__ unsigned int f2bf(float f) {
    unsigned int u = __float_as_uint(f);
    unsigned int r = u + 0x7FFFu + ((u >> 16) & 1u);   // round-to-nearest-even
    return r >> 16;
}

// ---- pack W_kv into MFMA A-frag lane order, SPLIT bf16 (hi + lo) ----------
__global__ __launch_bounds__(256) void k_wgpack(const float* __restrict__ W,
                                                unsigned short* __restrict__ wg) {
    int gid = blockIdx.x * 256 + threadIdx.x;     // 10*8*64 = 5120
    if (gid >= 5120) return;
    int lane = gid & 63;
    int mc   = (gid >> 6) & 7;
    int oct  = gid >> 9;
    int oc = oct * 16 + (lane & 15);
    int m0 = mc * 32 + (lane >> 4) * 8;
    unsigned short oh[8], ol[8];
#pragma unroll
    for (int j = 0; j < 8; ++j) {
        float wv = (oc < CC) ? W[(size_t)oc * MD + m0 + j] : 0.f;
        unsigned int hi = f2bf(wv);
        float r = wv - __uint_as_float(hi << 16);
        oh[j] = (unsigned short)hi;
        ol[j] = (unsigned short)f2bf(r);
    }
    ushort4* dh = (ushort4*)(wg + (size_t)gid * 8);
    dh[0] = make_ushort4(oh[0], oh[1], oh[2], oh[3]);
    dh[1] = make_ushort4(oh[4], oh[5], oh[6], oh[7]);
    ushort4* dl = (ushort4*)(wg + (size_t)(5120 + gid) * 8);
    dl[0] = make_ushort4(ol[0], ol[1], ol[2], ol[3]);
    dl[1] = make_ushort4(ol[4], ol[5], ol[6], ol[7]);
}

// ------ GEMM via split-bf16 MFMA: kv = W x, near-fp32 accurate -------------
__global__ __launch_bounds__(256) void k_gemm(const float* __restrict__ x,
                                              const unsigned short* __restrict__ wg,
                                              float* __restrict__ kv) {
    __shared__ __align__(16) unsigned char xh[32768];    // [64 n][256 m] bf16 swz
    __shared__ __align__(16) unsigned char xlo[32768];
    int nt = blockIdx.x;          // 0..63
    int b  = blockIdx.y;
    int tid = threadIdx.x;
    int n_l = tid & 63, w = tid >> 6;
    int n0 = nt * 64;

    const float* xb = x + (size_t)b * MD * NP + n0;
#pragma unroll 4
    for (int k = 0; k < 32; ++k) {
        int m = k * 8 + w * 2;
        float v0 = xb[(size_t)m * NP + n_l];
        float v1 = xb[(size_t)(m + 1) * NP + n_l];
        unsigned int h0 = f2bf(v0), h1 = f2bf(v1);
        float r0 = v0 - __uint_as_float(h0 << 16);
        float r1 = v1 - __uint_as_float(h1 << 16);
        unsigned int byte = (unsigned)(n_l * 512 + m * 2) ^ (unsigned)((n_l & 7) << 4);
        *(unsigned int*)(xh + byte)  = h0 | (h1 << 16);
        *(unsigned int*)(xlo + byte) = f2bf(r0) | (f2bf(r1) << 16);
    }
    __syncthreads();

    int lane = tid & 63;
    int nn = w * 16 + (lane & 15);
    int kg = lane >> 4;
    short8v xfh[8], xfl[8];
#pragma unroll
    for (int mc = 0; mc < 8; ++mc) {
        unsigned int byte = (unsigned)(nn * 512 + (mc * 32 + kg * 8) * 2)
                          ^ (unsigned)((nn & 7) << 4);
        xfh[mc] = *(const short8v*)(xh + byte);
        xfl[mc] = *(const short8v*)(xlo + byte);
    }

    f32x4 acc[10];
#pragma unroll
    for (int t = 0; t < 10; ++t) acc[t] = (f32x4){0.f, 0.f, 0.f, 0.f};

    const short8v* wfh = (const short8v*)wg;
    const short8v* wfl = wfh + 5120;
#pragma unroll
    for (int oct = 0; oct < 10; ++oct) {
#pragma unroll
        for (int mc = 0; mc < 8; ++mc) {
            short8v wh = wfh[(oct * 8 + mc) * 64 + lane];
            short8v wl = wfl[(oct * 8 + mc) * 64 + lane];
            acc[oct] = __builtin_amdgcn_mfma_f32_16x16x32_bf16(wh, xfh[mc], acc[oct], 0, 0, 0);
            acc[oct] = __builtin_amdgcn_mfma_f32_16x16x32_bf16(wh, xfl[mc], acc[oct], 0, 0, 0);
            acc[oct] = __builtin_amdgcn_mfma_f32_16x16x32_bf16(wl, xfh[mc], acc[oct], 0, 0, 0);
        }
    }

    int n = n0 + nn;
#pragma unroll
    for (int oct = 0; oct < 10; ++oct) {
#pragma unroll
        for (int r = 0; r < 4; ++r) {
            int oc = oct * 16 + kg * 4 + r;
            if (oc < CC)
                kv[((size_t)b * CC + oc) * NP + n] = acc[oct][r];
        }
    }
}

// ------------- BN stats over (B,N) for all 152 kv channels -----------------
__global__ __launch_bounds__(256) void k_stats_kv(const float* __restrict__ kv,
                                                  const float* __restrict__ kg,
                                                  const float* __restrict__ kb,
                                                  const float* __restrict__ vg,
                                                  const float* __restrict__ vb,
                                                  float* __restrict__ A,
                                                  float* __restrict__ Bv) {
    int o = blockIdx.x, tid = threadIdx.x;
    float s = 0.f, ss = 0.f;
    for (int b = 0; b < BB; ++b) {
        const float* p = kv + ((size_t)b * CC + o) * NP;
        for (int n = tid; n < NP; n += 256) { float v = p[n]; s += v; ss = fmaf(v, v, ss); }
    }
#pragma unroll
    for (int off = 32; off > 0; off >>= 1) { s += __shfl_down(s, off); ss += __shfl_down(ss, off); }
    __shared__ float sh[8];
    int lane = tid & 63, w = tid >> 6;
    if (lane == 0) { sh[w] = s; sh[4 + w] = ss; }
    __syncthreads();
    if (tid == 0) {
        float S_ = sh[0] + sh[1] + sh[2] + sh[3];
        float SSv = sh[4] + sh[5] + sh[6] + sh[7];
        float mean = S_ * (1.f / BN_CNT);
        float var  = SSv * (1.f / BN_CNT) - mean * mean;
        float rstd = rsqrtf(var + EPSV);
        float g  = (o < KC) ? kg[o] : vg[o - KC];
        float be = (o < KC) ? kb[o] : vb[o - KC];
        A[o]  = rstd * g;
        Bv[o] = be - mean * rstd * g;
    }
}

// --- per-point: BN keys -> affine -> tanh -> idx/frac; also emit vals[.,16] -
__global__ __launch_bounds__(256) void k_prep(const float* __restrict__ kv,
                                              const float* __restrict__ pcd,
                                              const float* __restrict__ A,
                                              const float* __restrict__ Bv,
                                              const float* __restrict__ R,
                                              const float* __restrict__ t,
                                              int* __restrict__ base,
                                              float* __restrict__ frac,
                                              float* __restrict__ vals) {
    int gid = blockIdx.x * 256 + threadIdx.x;
    int b = gid >> 15, h = (gid >> 12) & 7, n = gid & 4095;

    float p[3];
#pragma unroll
    for (int i = 0; i < 3; ++i) {
        int c = h * 3 + i;
        float v = kv[((size_t)b * CC + c) * NP + n];
        p[i] = pcd[((size_t)b * 3 + i) * NP + n] + fmaf(A[c], v, Bv[c]);
    }
    int fl[3]; float fr[3];
#pragma unroll
    for (int i = 0; i < 3; ++i) {
        float key = R[h * 9 + i * 3 + 0] * p[0] + R[h * 9 + i * 3 + 1] * p[1] +
                    R[h * 9 + i * 3 + 2] * p[2] + t[h * 3 + i];
        float lat = tanhf(key);
        float pos = (lat + 1.f) * 0.5f * (SS - 1);
        float flf = fminf(fmaxf(floorf(pos), 0.f), (float)(SS - 2));
        fr[i] = pos - flf;
        fl[i] = (int)flf;
    }
    base[gid] = (fl[0] * SS + fl[1]) * SS + fl[2];
    frac[gid]           = fr[0];
    frac[PTS + gid]     = fr[1];
    frac[2 * PTS + gid] = fr[2];

    float4* vo = (float4*)(vals + (size_t)gid * 16);
#pragma unroll
    for (int q = 0; q < 4; ++q) {
        float4 v;
        float* vv = (float*)&v;
#pragma unroll
        for (int j = 0; j < 4; ++j) {
            int c = KC + h * FF + q * 4 + j;
            vv[j] = fmaf(A[c], kv[((size_t)b * CC + c) * NP + n], Bv[c]);
        }
        vo[q] = v;
    }
}

// ---- counting sort per (b,h): 1024 (slab,y) bins -> sorted records --------
__global__ __launch_bounds__(256) void k_bin(const int* __restrict__ base,
                                             const float* __restrict__ frac,
                                             int4* __restrict__ sorted,
                                             int* __restrict__ bin_start) {
    __shared__ int hist[1024];
    __shared__ int curs[1024];
    int bh = blockIdx.x;           // b*8+h  (gid = bh*NP + n)
    int tid = threadIdx.x;
    for (int k = tid; k < 1024; k += 256) hist[k] = 0;
    __syncthreads();
    int gb = bh * NP;
    for (int p = tid; p < NP; p += 256)
        atomicAdd(&hist[base[gb + p] >> 5], 1);
    __syncthreads();
    if (tid == 0) {
        int run = 0;
        for (int k = 0; k < 1024; ++k) { int c = hist[k]; hist[k] = run; run += c; }
    }
    __syncthreads();
    for (int k = tid; k < 1024; k += 256) {
        bin_start[bh * 1024 + k] = hist[k];
        curs[k] = hist[k];
    }
    __syncthreads();
    for (int p = tid; p < NP; p += 256) {
        int bs = base[gb + p];
        int slot = atomicAdd(&curs[bs >> 5], 1);
        sorted[(size_t)bh * NP + slot] =
            make_int4(p | (bs << 12),
                      __float_as_int(frac[gb + p]),
                      __float_as_int(frac[PTS + gb + p]),
                      __float_as_int(frac[2 * PTS + gb + p]));
    }
}

// ---- permute vals into sorted order AND quantize to bf16 ------------------
// vals_s[j][ch] = bf16(vals[sorted[j].p][ch]); 2 threads per point (8 ch each)
__global__ __launch_bounds__(256) void k_vperm(const int4* __restrict__ sorted,
                                               const float* __restrict__ vals,
                                               unsigned short* __restrict__ vals_s) {
    int gid = blockIdx.x * 256 + threadIdx.x;    // over PTS*2 halves
    int j = gid >> 1, half = gid & 1;
    int bh = j >> 12;
    int p = sorted[j].x & 4095;
    const float4* src = (const float4*)(vals + ((size_t)bh * NP + p) * 16) + half * 2;
    float4 a = src[0], c = src[1];
    uint4 o;
    o.x = f2bf(a.x) | (f2bf(a.y) << 16);
    o.y = f2bf(a.z) | (f2bf(a.w) << 16);
    o.z = f2bf(c.x) | (f2bf(c.y) << 16);
    o.w = f2bf(c.z) | (f2bf(c.w) << 16);
    *(uint4*)(vals_s + (size_t)j * 16 + half * 8) = o;
}

// ---- pack conv weights into MFMA A-fragment lane order (bf16) -------------
__global__ __launch_bounds__(256) void k_wpack(const float* __restrict__ cw,
                                               unsigned short* __restrict__ wApack) {
    int gid = blockIdx.x * 256 + threadIdx.x;     // (h*14 + m)*64 + lane
    if (gid >= 8 * 14 * 64) return;
    int lane = gid & 63;
    int m = (gid >> 6) % 14;
    int h = gid / (14 * 64);
    int fo = lane & 15, g = lane >> 4;
    int tap = 2 * m + (g >> 1);
    int ci0 = (g & 1) * 8;
    unsigned short o[8];
#pragma unroll
    for (int j = 0; j < 8; ++j) {
        float w = (tap <= 26) ? cw[((size_t)(h * 16 + fo) * 16 + ci0 + j) * 27 + tap] : 0.f;
        o[j] = (unsigned short)f2bf(w);
    }
    ushort4* dst = (ushort4*)(wApack + (size_t)gid * 8);
    dst[0] = make_ushort4(o[0], o[1], o[2], o[3]);
    dst[1] = make_ushort4(o[4], o[5], o[6], o[7]);
}

// --- splat: SINGLE-WAVE blocks (x, y-quarter, h, bq); 64 thr, 8 KB LDS -----
// Wave owns rows [4*yq, 4*yq+4); 8-record batched predicated loads; bf16 vals
__global__ __launch_bounds__(64) void k_splat(const int4* __restrict__ sorted,
                                              const int* __restrict__ bin_start,
                                              const unsigned short* __restrict__ vsrc,
                                              unsigned short* __restrict__ zout,
                                              int b0) {
    __shared__ float zl[4][32][16];          // 8 KB fp32 accumulate
    int x  = blockIdx.x;          // 0..31 output plane
    int yq = blockIdx.y;          // 0..7  y quarter
    int hq = blockIdx.z;          // h + 8*bq
    int h = hq & 7, bq = hq >> 3;
    int bh = (b0 + bq) * 8 + h;
    int lane = threadIdx.x;       // 0..63
    int ch = lane & 15, cor = lane >> 4;
    int dyb = cor >> 1, dzb = cor & 1;
    int row_lo = yq * 4;          // wave owns global rows [row_lo, row_lo+4)
    int ylo = row_lo - 1; if (ylo < 0) ylo = 0;
    int yhi = row_lo + 4;         // <= 32 always

    float4* zl4 = (float4*)zl;
    float4 zero4 = make_float4(0.f, 0.f, 0.f, 0.f);
    for (int i = lane; i < 512; i += 64) zl4[i] = zero4;
    __syncthreads();

    const int4* srt = sorted + (size_t)bh * NP;
    const unsigned short* vb = vsrc + (size_t)bh * NP * 16;
    const int* bsrt = bin_start + bh * 1024;
    int yzoff = dyb * 32 + dzb - row_lo * 32;

#pragma unroll
    for (int pass = 0; pass < 2; ++pass) {
        int s = x - 1 + pass;      // pass0: dx=1 (slab x-1), pass1: dx=0 (slab x)
        if (s < 0 || s > 30) continue;
        int j0 = bsrt[s * 32 + ylo];
        int j1 = bsrt[s * 32 + yhi];
        bool dxh = (pass == 0);
        for (int j = j0; j < j1; j += 8) {
            int4 rec[8];
            float v[8];
#pragma unroll
            for (int u = 0; u < 8; ++u) {
                int jc = j + u; jc = (jc < NP - 1) ? jc : (NP - 1);
                rec[u] = srt[jc];
            }
#pragma unroll
            for (int u = 0; u < 8; ++u) {
                int jc = j + u; jc = (jc < NP - 1) ? jc : (NP - 1);
                v[u] = __uint_as_float((unsigned)vb[(size_t)jc * 16 + ch] << 16);
            }
#pragma unroll
            for (int u = 0; u < 8; ++u) {
                int bs = rec[u].x >> 12;
                int r = ((bs >> 5) & 31) + dyb;            // target y row
                if (j + u < j1 && (unsigned)(r - row_lo) < 4u) {
                    float fx = __int_as_float(rec[u].y);
                    float fy = __int_as_float(rec[u].z);
                    float fz = __int_as_float(rec[u].w);
                    float w = (dxh ? fx : 1.f - fx) * (dyb ? fy : 1.f - fy) *
                              (dzb ? fz : 1.f - fz);
                    int addr = (bs & 1023) + yzoff;        // local (row,z) index
                    (&zl[0][0][0])[addr * 16 + ch] += w * v[u];   // non-atomic RMW
                }
            }
        }
    }
    __syncthreads();

    // write quarter-plane as bf16: 128 cells x 32B
    for (int i = lane; i < 256; i += 64) {
        int cl = i >> 1, half = i & 1;
        float4 a = zl4[cl * 4 + half * 2];
        float4 c = zl4[cl * 4 + half * 2 + 1];
        uint4 o;
        o.x = f2bf(a.x) | (f2bf(a.y) << 16);
        o.y = f2bf(a.z) | (f2bf(a.w) << 16);
        o.z = f2bf(c.x) | (f2bf(c.y) << 16);
        o.w = f2bf(c.z) | (f2bf(c.w) << 16);
        int gcell = x * 1024 + row_lo * 32 + cl;
        *(uint4*)&zout[((size_t)(bq * HH + h) * S3 + gcell) * 16 + half * 8] = o;
    }
}

// ---- grouped 3x3x3 conv via bf16 MFMA; z bf16 in, zc bf16 OUT -------------
__global__ __launch_bounds__(256) void k_conv(const unsigned short* __restrict__ z,
                                              const unsigned short* __restrict__ wApack,
                                              const float* __restrict__ cb,
                                              unsigned short* __restrict__ zc) {
    __shared__ __align__(16) unsigned short zl[4][10][34][16];   // 43,520 B
    int bx = blockIdx.x;      // 0..15 -> x pair
    int yq = blockIdx.y;      // 0..3  -> 8 y rows
    int gz = blockIdx.z;      // h + 8*bq
    int h  = gz & 7;
    int bq = gz >> 3;
    int tid = threadIdx.x;
    int lane = tid & 63, wid = tid >> 6;
    int x2 = bx * 2;

    const unsigned short* zb = z + (size_t)bq * ZSTRH;
    unsigned short* zcb = zc + (size_t)bq * ZSTRH;

    short8v af[14];
    const short8v* wa = (const short8v*)(wApack + (size_t)h * 14 * 64 * 8);
#pragma unroll
    for (int m = 0; m < 14; ++m) af[m] = wa[m * 64 + lane];

    for (int i = tid; i < 4 * 10 * 34; i += 256) {
        int dxi = i / 340, rem = i % 340;
        int yy = rem / 34, zi = rem % 34;
        int gx = x2 + dxi - 1, gy = yq * 8 + yy - 1, gzz = zi - 1;
        uint4* d4 = (uint4*)(&zl[0][0][0][0] + (size_t)i * 16);
        if (gx >= 0 && gx < SS && gy >= 0 && gy < SS && gzz >= 0 && gzz < SS) {
            const uint4* src = (const uint4*)&zb[((size_t)h * S3 +
                                 (gx * 1024 + gy * 32 + gzz)) * 16];
            d4[0] = src[0];
            d4[1] = src[1];
        } else {
            uint4 zz4 = make_uint4(0, 0, 0, 0);
            d4[0] = zz4; d4[1] = zz4;
        }
    }
    __syncthreads();

    bool lo = (lane & 32) == 0;
    int ci0 = (lane & 16) ? 8 : 0;
    int l15 = lane & 15;
    int fo0 = (lane >> 4) * 4;
    float4 bias = *(const float4*)&cb[h * 16 + fo0];
    const unsigned short* zlf = &zl[0][0][0][0];

#pragma unroll 1
    for (int i = 0; i < 8; ++i) {
        int gi = wid * 8 + i;
        int xl = gi >> 4, yl = (gi >> 1) & 7, zz0 = (gi & 1) * 16;
        int invbase = xl * 340 + yl * 34 + zz0 + l15;

        f32x4 acc = {0.f, 0.f, 0.f, 0.f};
#pragma unroll
        for (int m = 0; m < 14; ++m) {
            const int t0 = 2 * m;
            const int t1 = (2 * m + 1 > 26) ? 26 : (2 * m + 1);
            const int off0 = (t0 / 9) * 340 + ((t0 % 9) / 3) * 34 + (t0 % 3);
            const int off1 = (t1 / 9) * 340 + ((t1 % 9) / 3) * 34 + (t1 % 3);
            int offc = lo ? off0 : off1;
            const short8v* bp = (const short8v*)(zlf + (size_t)(invbase + offc) * 16 + ci0);
            acc = __builtin_amdgcn_mfma_f32_16x16x32_bf16(af[m], *bp, acc, 0, 0, 0);
        }
        int cell = (x2 + xl) * 1024 + (yq * 8 + yl) * 32 + zz0 + l15;
        uint2 o;
        o.x = f2bf(acc[0] + bias.x) | (f2bf(acc[1] + bias.y) << 16);
        o.y = f2bf(acc[2] + bias.z) | (f2bf(acc[3] + bias.w) << 16);
        *(uint2*)&zcb[((size_t)h * S3 + cell) * 16 + fo0] = o;
    }
}

// --- slice: THREAD PER POINT; 8 corners x 32B loads; 16 coalesced stores ---
__global__ __launch_bounds__(256) void k_slice(const int* __restrict__ base,
                                               const float* __restrict__ frac,
                                               const unsigned short* __restrict__ zc,
                                               float* __restrict__ out, int b0) {
    int lid = blockIdx.x * 256 + threadIdx.x;   // 0..BPT-1
    int bq = blockIdx.y;
    int b = b0 + bq;
    int h = lid >> 12, n = lid & 4095;
    int gid = b * BPT + lid;
    int bs = base[gid];
    float fx = frac[gid], fy = frac[PTS + gid], fz = frac[2 * PTS + gid];
    float wx[2] = {1.f - fx, fx}, wy[2] = {1.f - fy, fy}, wz[2] = {1.f - fz, fz};
    const unsigned short* zb = zc + (size_t)bq * ZSTRH + (size_t)h * S3 * FF;

    float acc[16];
#pragma unroll
    for (int f = 0; f < 16; ++f) acc[f] = 0.f;
#pragma unroll
    for (int dx = 0; dx < 2; ++dx)
#pragma unroll
    for (int dy = 0; dy < 2; ++dy)
#pragma unroll
    for (int dz = 0; dz < 2; ++dz) {
        int cell = bs + dx * (SS * SS) + dy * SS + dz;
        float w = wx[dx] * wy[dy] * wz[dz];
        const uint4* src = (const uint4*)&zb[(size_t)cell * 16];
        uint4 u0 = src[0];
        uint4 u1 = src[1];
        acc[0]  = fmaf(__uint_as_float(u0.x << 16), w, acc[0]);
        acc[1]  = fmaf(__uint_as_float(u0.x & 0xffff0000u), w, acc[1]);
        acc[2]  = fmaf(__uint_as_float(u0.y << 16), w, acc[2]);
        acc[3]  = fmaf(__uint_as_float(u0.y & 0xffff0000u), w, acc[3]);
        acc[4]  = fmaf(__uint_as_float(u0.z << 16), w, acc[4]);
        acc[5]  = fmaf(__uint_as_float(u0.z & 0xffff0000u), w, acc[5]);
        acc[6]  = fmaf(__uint_as_float(u0.w << 16), w, acc[6]);
        acc[7]  = fmaf(__uint_as_float(u0.w & 0xffff0000u), w, acc[7]);
        acc[8]  = fmaf(__uint_as_float(u1.x << 16), w, acc[8]);
        acc[9]  = fmaf(__uint_as_float(u1.x & 0xffff0000u), w, acc[9]);
        acc[10] = fmaf(__uint_as_float(u1.y << 16), w, acc[10]);
        acc[11] = fmaf(__uint_as_float(u1.y & 0xffff0000u), w, acc[11]);
        acc[12] = fmaf(__uint_as_float(u1.z << 16), w, acc[12]);
        acc[13] = fmaf(__uint_as_float(u1.z & 0xffff0000u), w, acc[13]);
        acc[14] = fmaf(__uint_as_float(u1.w << 16), w, acc[14]);
        acc[15] = fmaf(__uint_as_float(u1.w & 0xffff0000u), w, acc[15]);
    }
    size_t ob = ((size_t)b * (HH * FF) + h * FF) * NP + n;
#pragma unroll
    for (int f = 0; f < 16; ++f)
        out[ob + (size_t)f * NP] = acc[f];
}

// ------------- BN stats over (B,N) for the 128 sliced channels -------------
__global__ __launch_bounds__(256) void k_stats2(const float* __restrict__ out,
                                                const float* __restrict__ ag,
                                                const float* __restrict__ ab,
                                                float* __restrict__ A2,
                                                float* __restrict__ B2) {
    int c = blockIdx.x, tid = threadIdx.x;
    float s = 0.f, ss = 0.f;
    for (int b = 0; b < BB; ++b) {
        const float* p = out + ((size_t)b * (HH * FF) + c) * NP;
        for (int n = tid; n < NP; n += 256) { float v = p[n]; s += v; ss = fmaf(v, v, ss); }
    }
#pragma unroll
    for (int off = 32; off > 0; off >>= 1) { s += __shfl_down(s, off); ss += __shfl_down(ss, off); }
    __shared__ float sh[8];
    int lane = tid & 63, w = tid >> 6;
    if (lane == 0) { sh[w] = s; sh[4 + w] = ss; }
    __syncthreads();
    if (tid == 0) {
        float S_ = sh[0] + sh[1] + sh[2] + sh[3];
        float SSv = sh[4] + sh[5] + sh[6] + sh[7];
        float mean = S_ * (1.f / BN_CNT);
        float var  = SSv * (1.f / BN_CNT) - mean * mean;
        float rstd = rsqrtf(var + EPSV);
        A2[c] = rstd * ag[c];
        B2[c] = ab[c] - mean * rstd * ag[c];
    }
}

// ---------------- final BN + ReLU in-place on d_out ------------------------
__global__ __launch_bounds__(256) void k_bnrelu(float* __restrict__ out,
                                                const float* __restrict__ A2,
                                                const float* __restrict__ B2) {
    int gid = blockIdx.x * 256 + threadIdx.x;
    int c = (gid >> 12) & 127;
    float v = out[gid];
    out[gid] = fmaxf(fmaf(A2[c], v, B2[c]), 0.f);
}

// ---------------------------------------------------------------------------
extern "C" void kernel_launch(void* const* d_in, const int* in_sizes, int n_in,
                              void* d_out, int out_size, void* d_ws, size_t ws_size,
                              hipStream_t stream) {
    (void)in_sizes; (void)n_in; (void)out_size;
    const float* x   = (const float*)d_in[0];
    const float* pcd = (const float*)d_in[1];
    const float* W   = (const float*)d_in[2];
    const float* kg  = (const float*)d_in[3];
    const float* kb  = (const float*)d_in[4];
    const float* vg  = (const float*)d_in[5];
    const float* vb  = (const float*)d_in[6];
    const float* R   = (const float*)d_in[7];
    const float* t   = (const float*)d_in[8];
    const float* cw  = (const float*)d_in[9];
    const float* cb  = (const float*)d_in[10];
    const float* ag  = (const float*)d_in[11];
    const float* ab  = (const float*)d_in[12];
    float* out = (float*)d_out;
    char* ws = (char*)d_ws;

    float* kv   = (float*)(ws + 0);            // 19,922,944; dead after k_prep
    int4*  sorted    = (int4*)(ws + 8388608ULL);   // 4 MB
    int*   bin_start = (int*) (ws + 12582912ULL);  // 256 KB
    unsigned short* wApack = (unsigned short*)(ws + 16777216ULL);
    int*   base = (int*)  (ws + 19922944ULL);
    float* frac = (float*)(ws + 20971520ULL);
    float* A    = (float*)(ws + 24117248ULL);
    float* Bv   = (float*)(ws + 24118272ULL);
    float* A2   = (float*)(ws + 24119296ULL);
    float* B2   = (float*)(ws + 24120320ULL);
    float* vals = (float*)(ws + 24121344ULL);  // 16,777,216 [point][16] fp32

    // per-batch: z_bf 8 MB + zc(bf16) 8 MB = 16 MB; + vals_s(bf16) 8.4 MB
    int NB = 1;
    if (ws_size >= 40898560ULL + 8ULL * 16777216ULL + 8388608ULL)      NB = 8;  // 183,500,800
    else if (ws_size >= 40898560ULL + 4ULL * 16777216ULL + 8388608ULL) NB = 4;
    else if (ws_size >= 40898560ULL + 2ULL * 16777216ULL + 8388608ULL) NB = 2;

    unsigned short* z_bf;
    unsigned short* zc;
    unsigned short* vals_s;
    if (NB == 1) {
        z_bf = (unsigned short*)kv;
        zc   = (unsigned short*)(ws + 40898560ULL);            // 8 MB
        vals_s = (unsigned short*)(ws + 49287168ULL);          // 8.4 MB -> end 57,675,776 (proven)
    } else {
        z_bf = (unsigned short*)(ws + 40898560ULL);                          // NB * 8 MB
        zc   = (unsigned short*)(ws + 40898560ULL + (size_t)NB * 8388608ULL);  // NB * 8 MB
        vals_s = (unsigned short*)(ws + 40898560ULL + (size_t)NB * 16777216ULL);
    }
    // GEMM W-pack (160 KB, hi+lo) aliases the zc region: written before
    // k_gemm, read only by k_gemm, clobbered later by k_conv.
    unsigned short* wg = (unsigned short*)zc;

    k_wgpack<<<dim3(20), 256, 0, stream>>>(W, wg);
    k_gemm<<<dim3(64, BB), 256, 0, stream>>>(x, wg, kv);
    k_stats_kv<<<dim3(CC), 256, 0, stream>>>(kv, kg, kb, vg, vb, A, Bv);
    k_prep<<<dim3(PTS / 256), 256, 0, stream>>>(kv, pcd, A, Bv, R, t, base, frac, vals);
    k_bin<<<dim3(BB * HH), 256, 0, stream>>>(base, frac, sorted, bin_start);
    k_vperm<<<dim3(PTS * 2 / 256), 256, 0, stream>>>(sorted, vals, vals_s);
    k_wpack<<<dim3(28), 256, 0, stream>>>(cw, wApack);

    for (int b0 = 0; b0 < BB; b0 += NB) {
        k_splat<<<dim3(SS, 8, HH * NB), 64, 0, stream>>>(sorted, bin_start, vals_s,
                                                         z_bf, b0);
        k_conv<<<dim3(16, 4, HH * NB), 256, 0, stream>>>(z_bf, wApack, cb, zc);
        k_slice<<<dim3(BPT / 256, NB), 256, 0, stream>>>(base, frac, zc, out, b0);
    }

    k_stats2<<<dim3(HH * FF), 256, 0, stream>>>(out, ag, ab, A2, B2);
    k_bnrelu<<<dim3((BB * HH * FF * NP) / 256), 256, 0, stream>>>(out, A2, B2);
}

// Round 21
// 262.610 us; speedup vs baseline: 1.2855x; 1.1561x over previous
//
#include <hip/hip_runtime.h>
#include <cstddef>
#include <cstdint>

#define BB 8
#define MD 256
#define NP 4096
#define HH 8
#define FF 16
#define SS 32
#define S3 32768
#define CC 152      // H*(F+3)
#define KC 24       // H*3
#define PTS (BB*HH*NP)   // 262144
#define BPT (HH*NP)      // points per batch = 32768
#define BN_CNT (BB*NP)   // 32768
#define EPSV 1e-5f
#define ZSTRH (HH*S3*FF)     // per-batch lattice ushorts (bf16) = 4,194,304 (8 MB)

typedef __attribute__((ext_vector_type(8))) short short8v;
typedef __attribute__((ext_vector_type(4))) float f32x4;

__device__ __forceinline__ unsigned int f2bf(float f) {
    unsigned int u = __float_as_uint(f);
    unsigned int r = u + 0x7FFFu + ((u >> 16) & 1u);   // round-to-nearest-even
    return r >> 16;
}

// ---- pack W_kv into MFMA A-frag lane order, SPLIT bf16 (hi + lo) ----------
__global__ __launch_bounds__(256) void k_wgpack(const float* __restrict__ W,
                                                unsigned short* __restrict__ wg) {
    int gid = blockIdx.x * 256 + threadIdx.x;     // 10*8*64 = 5120
    if (gid >= 5120) return;
    int lane = gid & 63;
    int mc   = (gid >> 6) & 7;
    int oct  = gid >> 9;
    int oc = oct * 16 + (lane & 15);
    int m0 = mc * 32 + (lane >> 4) * 8;
    unsigned short oh[8], ol[8];
#pragma unroll
    for (int j = 0; j < 8; ++j) {
        float wv = (oc < CC) ? W[(size_t)oc * MD + m0 + j] : 0.f;
        unsigned int hi = f2bf(wv);
        float r = wv - __uint_as_float(hi << 16);
        oh[j] = (unsigned short)hi;
        ol[j] = (unsigned short)f2bf(r);
    }
    ushort4* dh = (ushort4*)(wg + (size_t)gid * 8);
    dh[0] = make_ushort4(oh[0], oh[1], oh[2], oh[3]);
    dh[1] = make_ushort4(oh[4], oh[5], oh[6], oh[7]);
    ushort4* dl = (ushort4*)(wg + (size_t)(5120 + gid) * 8);
    dl[0] = make_ushort4(ol[0], ol[1], ol[2], ol[3]);
    dl[1] = make_ushort4(ol[4], ol[5], ol[6], ol[7]);
}

// ------ GEMM via split-bf16 MFMA: kv = W x, near-fp32 accurate -------------
__global__ __launch_bounds__(256) void k_gemm(const float* __restrict__ x,
                                              const unsigned short* __restrict__ wg,
                                              float* __restrict__ kv) {
    __shared__ __align__(16) unsigned char xh[32768];    // [64 n][256 m] bf16 swz
    __shared__ __align__(16) unsigned char xlo[32768];
    int nt = blockIdx.x;          // 0..63
    int b  = blockIdx.y;
    int tid = threadIdx.x;
    int n_l = tid & 63, w = tid >> 6;
    int n0 = nt * 64;

    const float* xb = x + (size_t)b * MD * NP + n0;
#pragma unroll 4
    for (int k = 0; k < 32; ++k) {
        int m = k * 8 + w * 2;
        float v0 = xb[(size_t)m * NP + n_l];
        float v1 = xb[(size_t)(m + 1) * NP + n_l];
        unsigned int h0 = f2bf(v0), h1 = f2bf(v1);
        float r0 = v0 - __uint_as_float(h0 << 16);
        float r1 = v1 - __uint_as_float(h1 << 16);
        unsigned int byte = (unsigned)(n_l * 512 + m * 2) ^ (unsigned)((n_l & 7) << 4);
        *(unsigned int*)(xh + byte)  = h0 | (h1 << 16);
        *(unsigned int*)(xlo + byte) = f2bf(r0) | (f2bf(r1) << 16);
    }
    __syncthreads();

    int lane = tid & 63;
    int nn = w * 16 + (lane & 15);
    int kg = lane >> 4;
    short8v xfh[8], xfl[8];
#pragma unroll
    for (int mc = 0; mc < 8; ++mc) {
        unsigned int byte = (unsigned)(nn * 512 + (mc * 32 + kg * 8) * 2)
                          ^ (unsigned)((nn & 7) << 4);
        xfh[mc] = *(const short8v*)(xh + byte);
        xfl[mc] = *(const short8v*)(xlo + byte);
    }

    f32x4 acc[10];
#pragma unroll
    for (int t = 0; t < 10; ++t) acc[t] = (f32x4){0.f, 0.f, 0.f, 0.f};

    const short8v* wfh = (const short8v*)wg;
    const short8v* wfl = wfh + 5120;
#pragma unroll
    for (int oct = 0; oct < 10; ++oct) {
#pragma unroll
        for (int mc = 0; mc < 8; ++mc) {
            short8v wh = wfh[(oct * 8 + mc) * 64 + lane];
            short8v wl = wfl[(oct * 8 + mc) * 64 + lane];
            acc[oct] = __builtin_amdgcn_mfma_f32_16x16x32_bf16(wh, xfh[mc], acc[oct], 0, 0, 0);
            acc[oct] = __builtin_amdgcn_mfma_f32_16x16x32_bf16(wh, xfl[mc], acc[oct], 0, 0, 0);
            acc[oct] = __builtin_amdgcn_mfma_f32_16x16x32_bf16(wl, xfh[mc], acc[oct], 0, 0, 0);
        }
    }

    int n = n0 + nn;
#pragma unroll
    for (int oct = 0; oct < 10; ++oct) {
#pragma unroll
        for (int r = 0; r < 4; ++r) {
            int oc = oct * 16 + kg * 4 + r;
            if (oc < CC)
                kv[((size_t)b * CC + oc) * NP + n] = acc[oct][r];
        }
    }
}

// ------------- BN stats over (B,N) for all 152 kv channels -----------------
__global__ __launch_bounds__(256) void k_stats_kv(const float* __restrict__ kv,
                                                  const float* __restrict__ kg,
                                                  const float* __restrict__ kb,
                                                  const float* __restrict__ vg,
                                                  const float* __restrict__ vb,
                                                  float* __restrict__ A,
                                                  float* __restrict__ Bv) {
    int o = blockIdx.x, tid = threadIdx.x;
    float s = 0.f, ss = 0.f;
    for (int b = 0; b < BB; ++b) {
        const float* p = kv + ((size_t)b * CC + o) * NP;
        for (int n = tid; n < NP; n += 256) { float v = p[n]; s += v; ss = fmaf(v, v, ss); }
    }
#pragma unroll
    for (int off = 32; off > 0; off >>= 1) { s += __shfl_down(s, off); ss += __shfl_down(ss, off); }
    __shared__ float sh[8];
    int lane = tid & 63, w = tid >> 6;
    if (lane == 0) { sh[w] = s; sh[4 + w] = ss; }
    __syncthreads();
    if (tid == 0) {
        float S_ = sh[0] + sh[1] + sh[2] + sh[3];
        float SSv = sh[4] + sh[5] + sh[6] + sh[7];
        float mean = S_ * (1.f / BN_CNT);
        float var  = SSv * (1.f / BN_CNT) - mean * mean;
        float rstd = rsqrtf(var + EPSV);
        float g  = (o < KC) ? kg[o] : vg[o - KC];
        float be = (o < KC) ? kb[o] : vb[o - KC];
        A[o]  = rstd * g;
        Bv[o] = be - mean * rstd * g;
    }
}

// --- per-point: BN keys -> affine -> tanh -> idx/frac; vals emitted bf16 ---
__global__ __launch_bounds__(256) void k_prep(const float* __restrict__ kv,
                                              const float* __restrict__ pcd,
                                              const float* __restrict__ A,
                                              const float* __restrict__ Bv,
                                              const float* __restrict__ R,
                                              const float* __restrict__ t,
                                              int* __restrict__ base,
                                              float* __restrict__ frac,
                                              unsigned short* __restrict__ vals) {
    int gid = blockIdx.x * 256 + threadIdx.x;
    int b = gid >> 15, h = (gid >> 12) & 7, n = gid & 4095;

    float p[3];
#pragma unroll
    for (int i = 0; i < 3; ++i) {
        int c = h * 3 + i;
        float v = kv[((size_t)b * CC + c) * NP + n];
        p[i] = pcd[((size_t)b * 3 + i) * NP + n] + fmaf(A[c], v, Bv[c]);
    }
    int fl[3]; float fr[3];
#pragma unroll
    for (int i = 0; i < 3; ++i) {
        float key = R[h * 9 + i * 3 + 0] * p[0] + R[h * 9 + i * 3 + 1] * p[1] +
                    R[h * 9 + i * 3 + 2] * p[2] + t[h * 3 + i];
        float lat = tanhf(key);
        float pos = (lat + 1.f) * 0.5f * (SS - 1);
        float flf = fminf(fmaxf(floorf(pos), 0.f), (float)(SS - 2));
        fr[i] = pos - flf;
        fl[i] = (int)flf;
    }
    base[gid] = (fl[0] * SS + fl[1]) * SS + fl[2];
    frac[gid]           = fr[0];
    frac[PTS + gid]     = fr[1];
    frac[2 * PTS + gid] = fr[2];

    float vv[16];
#pragma unroll
    for (int f = 0; f < 16; ++f) {
        int c = KC + h * FF + f;
        vv[f] = fmaf(A[c], kv[((size_t)b * CC + c) * NP + n], Bv[c]);
    }
    uint4* vo = (uint4*)(vals + (size_t)gid * 16);
#pragma unroll
    for (int q = 0; q < 2; ++q) {
        uint4 o;
        o.x = f2bf(vv[q * 8 + 0]) | (f2bf(vv[q * 8 + 1]) << 16);
        o.y = f2bf(vv[q * 8 + 2]) | (f2bf(vv[q * 8 + 3]) << 16);
        o.z = f2bf(vv[q * 8 + 4]) | (f2bf(vv[q * 8 + 5]) << 16);
        o.w = f2bf(vv[q * 8 + 6]) | (f2bf(vv[q * 8 + 7]) << 16);
        vo[q] = o;
    }
}

// ---- counting sort per (b,h): 1024 (slab,y) bins; also permutes bf16 vals -
__global__ __launch_bounds__(256) void k_bin(const int* __restrict__ base,
                                             const float* __restrict__ frac,
                                             const unsigned short* __restrict__ vals,
                                             int4* __restrict__ sorted,
                                             int* __restrict__ bin_start,
                                             unsigned short* __restrict__ vals_s) {
    __shared__ int hist[1024];
    __shared__ int curs[1024];
    int bh = blockIdx.x;           // b*8+h  (gid = bh*NP + n)
    int tid = threadIdx.x;
    for (int k = tid; k < 1024; k += 256) hist[k] = 0;
    __syncthreads();
    int gb = bh * NP;
    for (int p = tid; p < NP; p += 256)
        atomicAdd(&hist[base[gb + p] >> 5], 1);
    __syncthreads();
    if (tid == 0) {
        int run = 0;
        for (int k = 0; k < 1024; ++k) { int c = hist[k]; hist[k] = run; run += c; }
    }
    __syncthreads();
    for (int k = tid; k < 1024; k += 256) {
        bin_start[bh * 1024 + k] = hist[k];
        curs[k] = hist[k];
    }
    __syncthreads();
    for (int p = tid; p < NP; p += 256) {
        int bs = base[gb + p];
        int slot = atomicAdd(&curs[bs >> 5], 1);
        sorted[(size_t)bh * NP + slot] =
            make_int4(p | (bs << 12),
                      __float_as_int(frac[gb + p]),
                      __float_as_int(frac[PTS + gb + p]),
                      __float_as_int(frac[2 * PTS + gb + p]));
        const uint4* vsrc = (const uint4*)(vals + (size_t)(gb + p) * 16);
        uint4* vdst = (uint4*)(vals_s + ((size_t)bh * NP + slot) * 16);
        vdst[0] = vsrc[0];
        vdst[1] = vsrc[1];
    }
}

// ---- pack conv weights into MFMA A-fragment lane order (bf16) -------------
__global__ __launch_bounds__(256) void k_wpack(const float* __restrict__ cw,
                                               unsigned short* __restrict__ wApack) {
    int gid = blockIdx.x * 256 + threadIdx.x;     // (h*14 + m)*64 + lane
    if (gid >= 8 * 14 * 64) return;
    int lane = gid & 63;
    int m = (gid >> 6) % 14;
    int h = gid / (14 * 64);
    int fo = lane & 15, g = lane >> 4;
    int tap = 2 * m + (g >> 1);
    int ci0 = (g & 1) * 8;
    unsigned short o[8];
#pragma unroll
    for (int j = 0; j < 8; ++j) {
        float w = (tap <= 26) ? cw[((size_t)(h * 16 + fo) * 16 + ci0 + j) * 27 + tap] : 0.f;
        o[j] = (unsigned short)f2bf(w);
    }
    ushort4* dst = (ushort4*)(wApack + (size_t)gid * 8);
    dst[0] = make_ushort4(o[0], o[1], o[2], o[3]);
    dst[1] = make_ushort4(o[4], o[5], o[6], o[7]);
}

// ---- zero the 256-float BN accumulator (sums + sumsq) ---------------------
__global__ __launch_bounds__(256) void k_zero(float* __restrict__ sums) {
    sums[threadIdx.x] = 0.f;
}

// --- splat: SINGLE-WAVE blocks (x, y-quarter, h, bq); 64 thr, 8 KB LDS -----
__global__ __launch_bounds__(64) void k_splat(const int4* __restrict__ sorted,
                                              const int* __restrict__ bin_start,
                                              const unsigned short* __restrict__ vsrc,
                                              unsigned short* __restrict__ zout,
                                              int b0) {
    __shared__ float zl[4][32][16];          // 8 KB fp32 accumulate
    int x  = blockIdx.x;          // 0..31 output plane
    int yq = blockIdx.y;          // 0..7  y quarter
    int hq = blockIdx.z;          // h + 8*bq
    int h = hq & 7, bq = hq >> 3;
    int bh = (b0 + bq) * 8 + h;
    int lane = threadIdx.x;       // 0..63
    int ch = lane & 15, cor = lane >> 4;
    int dyb = cor >> 1, dzb = cor & 1;
    int row_lo = yq * 4;          // wave owns global rows [row_lo, row_lo+4)
    int ylo = row_lo - 1; if (ylo < 0) ylo = 0;
    int yhi = row_lo + 4;         // <= 32 always

    float4* zl4 = (float4*)zl;
    float4 zero4 = make_float4(0.f, 0.f, 0.f, 0.f);
    for (int i = lane; i < 512; i += 64) zl4[i] = zero4;
    __syncthreads();

    const int4* srt = sorted + (size_t)bh * NP;
    const unsigned short* vb = vsrc + (size_t)bh * NP * 16;
    const int* bsrt = bin_start + bh * 1024;
    int yzoff = dyb * 32 + dzb - row_lo * 32;

#pragma unroll
    for (int pass = 0; pass < 2; ++pass) {
        int s = x - 1 + pass;      // pass0: dx=1 (slab x-1), pass1: dx=0 (slab x)
        if (s < 0 || s > 30) continue;
        int j0 = bsrt[s * 32 + ylo];
        int j1 = bsrt[s * 32 + yhi];
        bool dxh = (pass == 0);
        for (int j = j0; j < j1; j += 8) {
            int4 rec[8];
            float v[8];
#pragma unroll
            for (int u = 0; u < 8; ++u) {
                int jc = j + u; jc = (jc < NP - 1) ? jc : (NP - 1);
                rec[u] = srt[jc];
            }
#pragma unroll
            for (int u = 0; u < 8; ++u) {
                int jc = j + u; jc = (jc < NP - 1) ? jc : (NP - 1);
                v[u] = __uint_as_float((unsigned)vb[(size_t)jc * 16 + ch] << 16);
            }
#pragma unroll
            for (int u = 0; u < 8; ++u) {
                int bs = rec[u].x >> 12;
                int r = ((bs >> 5) & 31) + dyb;            // target y row
                if (j + u < j1 && (unsigned)(r - row_lo) < 4u) {
                    float fx = __int_as_float(rec[u].y);
                    float fy = __int_as_float(rec[u].z);
                    float fz = __int_as_float(rec[u].w);
                    float w = (dxh ? fx : 1.f - fx) * (dyb ? fy : 1.f - fy) *
                              (dzb ? fz : 1.f - fz);
                    int addr = (bs & 1023) + yzoff;        // local (row,z) index
                    (&zl[0][0][0])[addr * 16 + ch] += w * v[u];   // non-atomic RMW
                }
            }
        }
    }
    __syncthreads();

    // write quarter-plane as bf16: 128 cells x 32B
    for (int i = lane; i < 256; i += 64) {
        int cl = i >> 1, half = i & 1;
        float4 a = zl4[cl * 4 + half * 2];
        float4 c = zl4[cl * 4 + half * 2 + 1];
        uint4 o;
        o.x = f2bf(a.x) | (f2bf(a.y) << 16);
        o.y = f2bf(a.z) | (f2bf(a.w) << 16);
        o.z = f2bf(c.x) | (f2bf(c.y) << 16);
        o.w = f2bf(c.z) | (f2bf(c.w) << 16);
        int gcell = x * 1024 + row_lo * 32 + cl;
        *(uint4*)&zout[((size_t)(bq * HH + h) * S3 + gcell) * 16 + half * 8] = o;
    }
}

// ---- grouped 3x3x3 conv via bf16 MFMA; z bf16 in, zc bf16 OUT -------------
__global__ __launch_bounds__(256) void k_conv(const unsigned short* __restrict__ z,
                                              const unsigned short* __restrict__ wApack,
                                              const float* __restrict__ cb,
                                              unsigned short* __restrict__ zc) {
    __shared__ __align__(16) unsigned short zl[4][10][34][16];   // 43,520 B
    int bx = blockIdx.x;      // 0..15 -> x pair
    int yq = blockIdx.y;      // 0..3  -> 8 y rows
    int gz = blockIdx.z;      // h + 8*bq
    int h  = gz & 7;
    int bq = gz >> 3;
    int tid = threadIdx.x;
    int lane = tid & 63, wid = tid >> 6;
    int x2 = bx * 2;

    const unsigned short* zb = z + (size_t)bq * ZSTRH;
    unsigned short* zcb = zc + (size_t)bq * ZSTRH;

    short8v af[14];
    const short8v* wa = (const short8v*)(wApack + (size_t)h * 14 * 64 * 8);
#pragma unroll
    for (int m = 0; m < 14; ++m) af[m] = wa[m * 64 + lane];

    for (int i = tid; i < 4 * 10 * 34; i += 256) {
        int dxi = i / 340, rem = i % 340;
        int yy = rem / 34, zi = rem % 34;
        int gx = x2 + dxi - 1, gy = yq * 8 + yy - 1, gzz = zi - 1;
        uint4* d4 = (uint4*)(&zl[0][0][0][0] + (size_t)i * 16);
        if (gx >= 0 && gx < SS && gy >= 0 && gy < SS && gzz >= 0 && gzz < SS) {
            const uint4* src = (const uint4*)&zb[((size_t)h * S3 +
                                 (gx * 1024 + gy * 32 + gzz)) * 16];
            d4[0] = src[0];
            d4[1] = src[1];
        } else {
            uint4 zz4 = make_uint4(0, 0, 0, 0);
            d4[0] = zz4; d4[1] = zz4;
        }
    }
    __syncthreads();

    bool lo = (lane & 32) == 0;
    int ci0 = (lane & 16) ? 8 : 0;
    int l15 = lane & 15;
    int fo0 = (lane >> 4) * 4;
    float4 bias = *(const float4*)&cb[h * 16 + fo0];
    const unsigned short* zlf = &zl[0][0][0][0];

#pragma unroll 1
    for (int i = 0; i < 8; ++i) {
        int gi = wid * 8 + i;
        int xl = gi >> 4, yl = (gi >> 1) & 7, zz0 = (gi & 1) * 16;
        int invbase = xl * 340 + yl * 34 + zz0 + l15;

        f32x4 acc = {0.f, 0.f, 0.f, 0.f};
#pragma unroll
        for (int m = 0; m < 14; ++m) {
            const int t0 = 2 * m;
            const int t1 = (2 * m + 1 > 26) ? 26 : (2 * m + 1);
            const int off0 = (t0 / 9) * 340 + ((t0 % 9) / 3) * 34 + (t0 % 3);
            const int off1 = (t1 / 9) * 340 + ((t1 % 9) / 3) * 34 + (t1 % 3);
            int offc = lo ? off0 : off1;
            const short8v* bp = (const short8v*)(zlf + (size_t)(invbase + offc) * 16 + ci0);
            acc = __builtin_amdgcn_mfma_f32_16x16x32_bf16(af[m], *bp, acc, 0, 0, 0);
        }
        int cell = (x2 + xl) * 1024 + (yq * 8 + yl) * 32 + zz0 + l15;
        uint2 o;
        o.x = f2bf(acc[0] + bias.x) | (f2bf(acc[1] + bias.y) << 16);
        o.y = f2bf(acc[2] + bias.z) | (f2bf(acc[3] + bias.w) << 16);
        *(uint2*)&zcb[((size_t)h * S3 + cell) * 16 + fo0] = o;
    }
}

// --- slice: THREAD PER POINT; also accumulates BN sums (block -> atomic) ---
__global__ __launch_bounds__(256) void k_slice(const int* __restrict__ base,
                                               const float* __restrict__ frac,
                                               const unsigned short* __restrict__ zc,
                                               float* __restrict__ out,
                                               float* __restrict__ sums, int b0) {
    __shared__ float shs[4][16];
    __shared__ float shq[4][16];
    int lid = blockIdx.x * 256 + threadIdx.x;   // 0..BPT-1
    int bq = blockIdx.y;
    int b = b0 + bq;
    int tid = threadIdx.x;
    int h = lid >> 12, n = lid & 4095;
    int gid = b * BPT + lid;
    int bs = base[gid];
    float fx = frac[gid], fy = frac[PTS + gid], fz = frac[2 * PTS + gid];
    float wx[2] = {1.f - fx, fx}, wy[2] = {1.f - fy, fy}, wz[2] = {1.f - fz, fz};
    const unsigned short* zb = zc + (size_t)bq * ZSTRH + (size_t)h * S3 * FF;

    float acc[16];
#pragma unroll
    for (int f = 0; f < 16; ++f) acc[f] = 0.f;
#pragma unroll
    for (int dx = 0; dx < 2; ++dx)
#pragma unroll
    for (int dy = 0; dy < 2; ++dy)
#pragma unroll
    for (int dz = 0; dz < 2; ++dz) {
        int cell = bs + dx * (SS * SS) + dy * SS + dz;
        float w = wx[dx] * wy[dy] * wz[dz];
        const uint4* src = (const uint4*)&zb[(size_t)cell * 16];
        uint4 u0 = src[0];
        uint4 u1 = src[1];
        acc[0]  = fmaf(__uint_as_float(u0.x << 16), w, acc[0]);
        acc[1]  = fmaf(__uint_as_float(u0.x & 0xffff0000u), w, acc[1]);
        acc[2]  = fmaf(__uint_as_float(u0.y << 16), w, acc[2]);
        acc[3]  = fmaf(__uint_as_float(u0.y & 0xffff0000u), w, acc[3]);
        acc[4]  = fmaf(__uint_as_float(u0.z << 16), w, acc[4]);
        acc[5]  = fmaf(__uint_as_float(u0.z & 0xffff0000u), w, acc[5]);
        acc[6]  = fmaf(__uint_as_float(u0.w << 16), w, acc[6]);
        acc[7]  = fmaf(__uint_as_float(u0.w & 0xffff0000u), w, acc[7]);
        acc[8]  = fmaf(__uint_as_float(u1.x << 16), w, acc[8]);
        acc[9]  = fmaf(__uint_as_float(u1.x & 0xffff0000u), w, acc[9]);
        acc[10] = fmaf(__uint_as_float(u1.y << 16), w, acc[10]);
        acc[11] = fmaf(__uint_as_float(u1.y & 0xffff0000u), w, acc[11]);
        acc[12] = fmaf(__uint_as_float(u1.z << 16), w, acc[12]);
        acc[13] = fmaf(__uint_as_float(u1.z & 0xffff0000u), w, acc[13]);
        acc[14] = fmaf(__uint_as_float(u1.w << 16), w, acc[14]);
        acc[15] = fmaf(__uint_as_float(u1.w & 0xffff0000u), w, acc[15]);
    }
    size_t ob = ((size_t)b * (HH * FF) + h * FF) * NP + n;
#pragma unroll
    for (int f = 0; f < 16; ++f)
        out[ob + (size_t)f * NP] = acc[f];

    // BN partial sums: all threads in this block share h
    float s[16], q[16];
#pragma unroll
    for (int f = 0; f < 16; ++f) { s[f] = acc[f]; q[f] = acc[f] * acc[f]; }
#pragma unroll
    for (int off = 32; off > 0; off >>= 1) {
#pragma unroll
        for (int f = 0; f < 16; ++f) {
            s[f] += __shfl_down(s[f], off);
            q[f] += __shfl_down(q[f], off);
        }
    }
    int lane = tid & 63, wid = tid >> 6;
    if (lane == 0) {
#pragma unroll
        for (int f = 0; f < 16; ++f) { shs[wid][f] = s[f]; shq[wid][f] = q[f]; }
    }
    __syncthreads();
    if (tid < 16) {
        float S = shs[0][tid] + shs[1][tid] + shs[2][tid] + shs[3][tid];
        atomicAdd(&sums[h * 16 + tid], S);
    } else if (tid < 32) {
        int f = tid - 16;
        float Q = shq[0][f] + shq[1][f] + shq[2][f] + shq[3][f];
        atomicAdd(&sums[128 + h * 16 + f], Q);
    }
}

// ------ finalize BN coefficients from accumulated sums (1 block) -----------
__global__ __launch_bounds__(128) void k_stats2fin(const float* __restrict__ sums,
                                                   const float* __restrict__ ag,
                                                   const float* __restrict__ ab,
                                                   float* __restrict__ A2,
                                                   float* __restrict__ B2) {
    int c = threadIdx.x;          // 0..127
    float mean = sums[c] * (1.f / BN_CNT);
    float var  = sums[128 + c] * (1.f / BN_CNT) - mean * mean;
    float rstd = rsqrtf(var + EPSV);
    A2[c] = rstd * ag[c];
    B2[c] = ab[c] - mean * rstd * ag[c];
}

// ---------------- final BN + ReLU in-place on d_out ------------------------
__global__ __launch_bounds__(256) void k_bnrelu(float* __restrict__ out,
                                                const float* __restrict__ A2,
                                                const float* __restrict__ B2) {
    int gid = blockIdx.x * 256 + threadIdx.x;
    int c = (gid >> 12) & 127;
    float v = out[gid];
    out[gid] = fmaxf(fmaf(A2[c], v, B2[c]), 0.f);
}

// ---------------------------------------------------------------------------
extern "C" void kernel_launch(void* const* d_in, const int* in_sizes, int n_in,
                              void* d_out, int out_size, void* d_ws, size_t ws_size,
                              hipStream_t stream) {
    (void)in_sizes; (void)n_in; (void)out_size;
    const float* x   = (const float*)d_in[0];
    const float* pcd = (const float*)d_in[1];
    const float* W   = (const float*)d_in[2];
    const float* kg  = (const float*)d_in[3];
    const float* kb  = (const float*)d_in[4];
    const float* vg  = (const float*)d_in[5];
    const float* vb  = (const float*)d_in[6];
    const float* R   = (const float*)d_in[7];
    const float* t   = (const float*)d_in[8];
    const float* cw  = (const float*)d_in[9];
    const float* cb  = (const float*)d_in[10];
    const float* ag  = (const float*)d_in[11];
    const float* ab  = (const float*)d_in[12];
    float* out = (float*)d_out;
    char* ws = (char*)d_ws;

    float* kv   = (float*)(ws + 0);            // 19,922,944; dead after k_prep
    int4*  sorted    = (int4*)(ws + 8388608ULL);   // 4 MB
    int*   bin_start = (int*) (ws + 12582912ULL);  // 256 KB
    unsigned short* wApack = (unsigned short*)(ws + 16777216ULL);
    int*   base = (int*)  (ws + 19922944ULL);
    float* frac = (float*)(ws + 20971520ULL);
    float* A    = (float*)(ws + 24117248ULL);
    float* Bv   = (float*)(ws + 24118272ULL);
    float* A2   = (float*)(ws + 24119296ULL);
    float* B2   = (float*)(ws + 24120320ULL);
    unsigned short* vals = (unsigned short*)(ws + 24121344ULL);  // 8,388,608 bf16 [point][16]
    float* sums = (float*)(ws + 32509952ULL);  // 1,024 (256 floats), inside old vals region

    // per-batch: z_bf 8 MB + zc(bf16) 8 MB = 16 MB; + vals_s(bf16) 8.4 MB
    int NB = 1;
    if (ws_size >= 40898560ULL + 8ULL * 16777216ULL + 8388608ULL)      NB = 8;  // 183,500,800
    else if (ws_size >= 40898560ULL + 4ULL * 16777216ULL + 8388608ULL) NB = 4;
    else if (ws_size >= 40898560ULL + 2ULL * 16777216ULL + 8388608ULL) NB = 2;

    unsigned short* z_bf;
    unsigned short* zc;
    unsigned short* vals_s;
    if (NB == 1) {
        z_bf = (unsigned short*)kv;
        zc   = (unsigned short*)(ws + 40898560ULL);            // 8 MB
        vals_s = (unsigned short*)(ws + 49287168ULL);          // 8.4 MB -> end 57,675,776 (proven)
    } else {
        z_bf = (unsigned short*)(ws + 40898560ULL);                          // NB * 8 MB
        zc   = (unsigned short*)(ws + 40898560ULL + (size_t)NB * 8388608ULL);  // NB * 8 MB
        vals_s = (unsigned short*)(ws + 40898560ULL + (size_t)NB * 16777216ULL);
    }
    // GEMM W-pack (160 KB, hi+lo) aliases the zc region: written before
    // k_gemm, read only by k_gemm, clobbered later by k_conv.
    unsigned short* wg = (unsigned short*)zc;

    k_wgpack<<<dim3(20), 256, 0, stream>>>(W, wg);
    k_gemm<<<dim3(64, BB), 256, 0, stream>>>(x, wg, kv);
    k_stats_kv<<<dim3(CC), 256, 0, stream>>>(kv, kg, kb, vg, vb, A, Bv);
    k_prep<<<dim3(PTS / 256), 256, 0, stream>>>(kv, pcd, A, Bv, R, t, base, frac, vals);
    k_bin<<<dim3(BB * HH), 256, 0, stream>>>(base, frac, vals, sorted, bin_start, vals_s);
    k_wpack<<<dim3(28), 256, 0, stream>>>(cw, wApack);
    k_zero<<<dim3(1), 256, 0, stream>>>(sums);

    for (int b0 = 0; b0 < BB; b0 += NB) {
        k_splat<<<dim3(SS, 8, HH * NB), 64, 0, stream>>>(sorted, bin_start, vals_s,
                                                         z_bf, b0);
        k_conv<<<dim3(16, 4, HH * NB), 256, 0, stream>>>(z_bf, wApack, cb, zc);
        k_slice<<<dim3(BPT / 256, NB), 256, 0, stream>>>(base, frac, zc, out, sums, b0);
    }

    k_stats2fin<<<dim3(1), 128, 0, stream>>>(sums, ag, ab, A2, B2);
    k_bnrelu<<<dim3((BB * HH * FF * NP) / 256), 256, 0, stream>>>(out, A2, B2);
}